// Round 2
// baseline (1373.558 us; speedup 1.0000x reference)
//
#include <hip/hip_runtime.h>

constexpr int BLK = 256;

static inline int cdiv(long long a, int b) { return (int)((a + b - 1) / b); }

// ---------------- small utility ----------------

__global__ void zero_buf(float* __restrict__ p, int n) {
    int i = blockIdx.x * blockDim.x + threadIdx.x;
    if (i < n) p[i] = 0.0f;
}

// ---------------- degree / edge prep ----------------

__global__ void deg_init(float* __restrict__ deg, int N) {
    for (int i = blockIdx.x * blockDim.x + threadIdx.x; i < N; i += gridDim.x * blockDim.x)
        deg[i] = 1.0f;  // self-loop
}

__global__ void deg_count(const int* __restrict__ dst, float* __restrict__ deg, int E) {
    for (int i = blockIdx.x * blockDim.x + threadIdx.x; i < E; i += gridDim.x * blockDim.x)
        atomicAdd(&deg[dst[i]], 1.0f);
}

__global__ void deg_rsqrt(float* __restrict__ deg, int N) {
    for (int i = blockIdx.x * blockDim.x + threadIdx.x; i < N; i += gridDim.x * blockDim.x)
        deg[i] = rsqrtf(deg[i]);
}

__global__ void edge_norm(const int* __restrict__ src, const int* __restrict__ dst,
                          const float* __restrict__ dis, float* __restrict__ nrm, int E) {
    for (int i = blockIdx.x * blockDim.x + threadIdx.x; i < E; i += gridDim.x * blockDim.x)
        nrm[i] = dis[src[i]] * dis[dst[i]];
}

// ---------------- GEMM: out[N,M] = in[N,K] @ W[K,M] (+bias) ----------------
// W cached in LDS. Thread per output element, grid-stride.

template <int K, int M>
__global__ void gemm_bias(const float* __restrict__ in, const float* __restrict__ W,
                          const float* __restrict__ bias, float* __restrict__ out, int N) {
    __shared__ float Wl[K * M];
    for (int i = threadIdx.x; i < K * M; i += blockDim.x) Wl[i] = W[i];
    __syncthreads();
    int total = N * M;
    for (int idx = blockIdx.x * blockDim.x + threadIdx.x; idx < total;
         idx += gridDim.x * blockDim.x) {
        int r = idx / M, c = idx - r * M;
        const float* row = in + (long long)r * K;
        float acc = bias ? bias[c] : 0.0f;
#pragma unroll 8
        for (int k = 0; k < K; ++k) acc = fmaf(row[k], Wl[k * M + c], acc);
        out[idx] = acc;
    }
}

// ---------------- scatter: self-loop init + edge atomic add ----------------

template <int M>
__global__ void scatter_init(const float* __restrict__ xw, const float* __restrict__ dis,
                             const float* __restrict__ bias, float* __restrict__ out, int N) {
    int total = N * M;
    for (int i = blockIdx.x * blockDim.x + threadIdx.x; i < total; i += gridDim.x * blockDim.x) {
        int r = i / M, f = i - r * M;
        float d = dis[r];
        out[i] = fmaf(xw[i], d * d, bias[f]);
    }
}

template <int M>
__global__ void scatter_edges(const float* __restrict__ xw, const int* __restrict__ src,
                              const int* __restrict__ dst, const float* __restrict__ nrm,
                              float* __restrict__ out, int E) {
    long long total = (long long)E * M;
    for (long long i = blockIdx.x * (long long)blockDim.x + threadIdx.x; i < total;
         i += (long long)gridDim.x * blockDim.x) {
        int e = (int)(i / M), f = (int)(i - (long long)e * M);
        int s = src[e], d = dst[e];
        atomicAdd(&out[(long long)d * M + f], xw[(long long)s * M + f] * nrm[e]);
    }
}

// ---------------- BatchNorm (training mode, biased var) ----------------

template <int M>
__global__ void bn_stats(const float* __restrict__ h, float* __restrict__ sums, int N) {
    __shared__ float s[M], q[M];
    for (int i = threadIdx.x; i < M; i += blockDim.x) { s[i] = 0.0f; q[i] = 0.0f; }
    __syncthreads();
    int total = N * M;
    for (int idx = blockIdx.x * blockDim.x + threadIdx.x; idx < total;
         idx += gridDim.x * blockDim.x) {
        float v = h[idx];
        int c = idx % M;
        atomicAdd(&s[c], v);
        atomicAdd(&q[c], v * v);
    }
    __syncthreads();
    for (int i = threadIdx.x; i < M; i += blockDim.x) {
        atomicAdd(&sums[i], s[i]);
        atomicAdd(&sums[M + i], q[i]);
    }
}

template <int M>
__global__ void bn_finalize(const float* __restrict__ sums, const float* __restrict__ gamma,
                            const float* __restrict__ beta, float* __restrict__ ss, int N) {
    int i = threadIdx.x;
    if (i < M) {
        float inv_n = 1.0f / (float)N;
        float mean = sums[i] * inv_n;
        float var = sums[M + i] * inv_n - mean * mean;
        float sc = gamma[i] * rsqrtf(var + 1e-5f);
        ss[i] = sc;
        ss[M + i] = beta[i] - mean * sc;
    }
}

template <int M, bool RELU>
__global__ void bn_apply(float* __restrict__ h, const float* __restrict__ ss, int N) {
    int total = N * M;
    for (int idx = blockIdx.x * blockDim.x + threadIdx.x; idx < total;
         idx += gridDim.x * blockDim.x) {
        int c = idx % M;
        float v = fmaf(h[idx], ss[c], ss[M + c]);
        h[idx] = RELU ? fmaxf(v, 0.0f) : v;
    }
}

// ---------------- row-wise L2 normalize (M=64, wave per row) ----------------

__global__ void l2norm64(float* __restrict__ z, int N) {
    int row = blockIdx.x * (blockDim.x >> 6) + (threadIdx.x >> 6);
    int lane = threadIdx.x & 63;
    if (row >= N) return;
    float v = z[row * 64 + lane];
    float sq = v * v;
#pragma unroll
    for (int o = 32; o > 0; o >>= 1) sq += __shfl_xor(sq, o, 64);
    float nrm = sqrtf(sq);
    z[row * 64 + lane] = v / fmaxf(nrm, 1e-12f);
}

// ---------------- launch ----------------

extern "C" void kernel_launch(void* const* d_in, const int* in_sizes, int n_in,
                              void* d_out, int out_size, void* d_ws, size_t ws_size,
                              hipStream_t stream) {
    const float* x   = (const float*)d_in[0];
    const int*   ei  = (const int*)d_in[1];   // int32 per harness contract
    const float* W1  = (const float*)d_in[2];
    const float* b1  = (const float*)d_in[3];
    const float* g1  = (const float*)d_in[4];
    const float* be1 = (const float*)d_in[5];
    const float* W2  = (const float*)d_in[6];
    const float* b2  = (const float*)d_in[7];
    const float* g2  = (const float*)d_in[8];
    const float* be2 = (const float*)d_in[9];
    const float* Wp1 = (const float*)d_in[10];
    const float* bp1 = (const float*)d_in[11];
    const float* gp  = (const float*)d_in[12];
    const float* bep = (const float*)d_in[13];
    const float* Wp2 = (const float*)d_in[14];
    const float* bp2 = (const float*)d_in[15];

    const int N = in_sizes[0] / 128;   // 50000
    const int E = in_sizes[1] / 2;     // 800000
    const int* src = ei;
    const int* dst = ei + E;

    // workspace layout (floats): N + E + 2*N*96 + 384  ~= 42 MB
    float* ws   = (float*)d_ws;
    float* dis  = ws;                       // N
    float* nrm  = dis + N;                  // E
    float* buf1 = nrm + E;                  // N*96
    float* buf2 = buf1 + (long long)N * 96; // N*96
    float* sums = buf2 + (long long)N * 96; // 192
    float* ss   = sums + 192;               // 192

    float* out = (float*)d_out;             // N*64

    const int gN   = cdiv(N, BLK);
    const int gE   = cdiv(E, BLK);
    const int gNM  = min(cdiv((long long)N * 96, BLK), 8192);
    const int gEM  = min(cdiv((long long)E * 96, BLK), 32768);
    const int gGem = 2048;

    // degree + per-edge norm (shared by both layers)
    deg_init<<<gN, BLK, 0, stream>>>(dis, N);
    deg_count<<<gE, BLK, 0, stream>>>(dst, dis, E);
    deg_rsqrt<<<gN, BLK, 0, stream>>>(dis, N);
    edge_norm<<<gE, BLK, 0, stream>>>(src, dst, dis, nrm, E);

    // ---- GCN layer 1 ----
    gemm_bias<128, 96><<<gGem, BLK, 0, stream>>>(x, W1, nullptr, buf1, N);
    scatter_init<96><<<gNM, BLK, 0, stream>>>(buf1, dis, b1, buf2, N);
    scatter_edges<96><<<gEM, BLK, 0, stream>>>(buf1, src, dst, nrm, buf2, E);
    zero_buf<<<1, 192, 0, stream>>>(sums, 192);
    bn_stats<96><<<4096, BLK, 0, stream>>>(buf2, sums, N);
    bn_finalize<96><<<1, 128, 0, stream>>>(sums, g1, be1, ss, N);
    bn_apply<96, true><<<gNM, BLK, 0, stream>>>(buf2, ss, N);

    // ---- GCN layer 2 ----
    gemm_bias<96, 96><<<gGem, BLK, 0, stream>>>(buf2, W2, nullptr, buf1, N);
    scatter_init<96><<<gNM, BLK, 0, stream>>>(buf1, dis, b2, buf2, N);
    scatter_edges<96><<<gEM, BLK, 0, stream>>>(buf1, src, dst, nrm, buf2, E);
    zero_buf<<<1, 192, 0, stream>>>(sums, 192);
    bn_stats<96><<<4096, BLK, 0, stream>>>(buf2, sums, N);
    bn_finalize<96><<<1, 128, 0, stream>>>(sums, g2, be2, ss, N);
    bn_apply<96, true><<<gNM, BLK, 0, stream>>>(buf2, ss, N);

    // ---- projector ----
    gemm_bias<96, 96><<<gGem, BLK, 0, stream>>>(buf2, Wp1, bp1, buf1, N);
    zero_buf<<<1, 192, 0, stream>>>(sums, 192);
    bn_stats<96><<<4096, BLK, 0, stream>>>(buf1, sums, N);
    bn_finalize<96><<<1, 128, 0, stream>>>(sums, gp, bep, ss, N);
    bn_apply<96, true><<<gNM, BLK, 0, stream>>>(buf1, ss, N);

    gemm_bias<96, 64><<<gGem, BLK, 0, stream>>>(buf1, Wp2, bp2, out, N);
    l2norm64<<<cdiv(N, 4), BLK, 0, stream>>>(out, N);
}

// Round 4
// 745.496 us; speedup vs baseline: 1.8425x; 1.8425x over previous
//
#include <hip/hip_runtime.h>

constexpr int BLK = 256;

static inline int cdiv(long long a, int b) { return (int)((a + b - 1) / b); }

// ---------------- utility ----------------

__global__ void zero_int(int* __restrict__ p, int n) {
    for (int i = blockIdx.x * blockDim.x + threadIdx.x; i < n; i += gridDim.x * blockDim.x)
        p[i] = 0;
}

__global__ void zero_f(float* __restrict__ p, int n) {
    for (int i = blockIdx.x * blockDim.x + threadIdx.x; i < n; i += gridDim.x * blockDim.x)
        p[i] = 0.0f;
}

// ---------------- degree / CSR build ----------------

__global__ void count_dst(const int* __restrict__ dst, int* __restrict__ cnt, int E) {
    for (int i = blockIdx.x * blockDim.x + threadIdx.x; i < E; i += gridDim.x * blockDim.x)
        atomicAdd(&cnt[dst[i]], 1);
}

__global__ void dis_k(const int* __restrict__ cnt, float* __restrict__ dis, int N) {
    for (int i = blockIdx.x * blockDim.x + threadIdx.x; i < N; i += gridDim.x * blockDim.x)
        dis[i] = rsqrtf((float)cnt[i] + 1.0f);  // +1 self-loop
}

// block scans 1024 elements (256 threads x 4)
__global__ void scan1(const int* __restrict__ cnt, int* __restrict__ rowptr,
                      int* __restrict__ bsum, int N) {
    __shared__ int ts[256];
    int tid = threadIdx.x;
    int base = blockIdx.x * 1024 + tid * 4;
    int v[4], s = 0;
#pragma unroll
    for (int i = 0; i < 4; ++i) {
        v[i] = (base + i < N) ? cnt[base + i] : 0;
        s += v[i];
    }
    ts[tid] = s;
    __syncthreads();
    for (int off = 1; off < 256; off <<= 1) {
        int t = 0;
        if (tid >= off) t = ts[tid - off];
        __syncthreads();
        if (tid >= off) ts[tid] += t;
        __syncthreads();
    }
    int run = ts[tid] - s;  // exclusive prefix for this thread
#pragma unroll
    for (int i = 0; i < 4; ++i) {
        if (base + i < N) rowptr[base + i] = run;
        run += v[i];
    }
    if (tid == 255) bsum[blockIdx.x] = ts[255];
}

__global__ void scan2(const int* __restrict__ bsum, int* __restrict__ boff, int nb) {
    if (threadIdx.x == 0) {
        int r = 0;
        for (int i = 0; i < nb; ++i) { boff[i] = r; r += bsum[i]; }
    }
}

__global__ void scan3(int* __restrict__ rowptr, const int* __restrict__ boff, int N, int E) {
    int i = blockIdx.x * blockDim.x + threadIdx.x;
    if (i < N) rowptr[i] += boff[i >> 10];
    if (i == 0) rowptr[N] = E;
}

__global__ void csr_fill(const int* __restrict__ src, const int* __restrict__ dst,
                         const int* __restrict__ rowptr, int* __restrict__ cur,
                         const float* __restrict__ dis, int* __restrict__ csrc,
                         float* __restrict__ cnrm, int E) {
    for (int i = blockIdx.x * blockDim.x + threadIdx.x; i < E; i += gridDim.x * blockDim.x) {
        int s = src[i], d = dst[i];
        int slot = rowptr[d] + atomicAdd(&cur[d], 1);
        csrc[slot] = s;
        cnrm[slot] = dis[s] * dis[d];
    }
}

// ---------------- tiled GEMM: out[N,96] = act(in)[N,K] @ W[K,96] (+bias) ----
// act = relu(x*ss[k] + ss[96+k]) when ACT. Block: 64 rows x 96 cols, thread 4x6.

template <int K, bool ACT, bool BIAS>
__global__ __launch_bounds__(256) void gemm96(const float* __restrict__ in,
                                              const float* __restrict__ W,
                                              const float* __restrict__ bias,
                                              const float* __restrict__ ss,
                                              float* __restrict__ out, int N) {
    constexpr int KC = 32, PITCH = 68;
    __shared__ float Wl[K * 96];
    __shared__ float As[KC * PITCH];
    const int tid = threadIdx.x;
    for (int f = tid; f < K * 96 / 4; f += 256)
        ((float4*)Wl)[f] = ((const float4*)W)[f];
    const int n0 = blockIdx.x * 64;
    const int tx = tid & 15, ty = tid >> 4;
    float acc[4][6];
#pragma unroll
    for (int r = 0; r < 4; ++r)
#pragma unroll
        for (int j = 0; j < 6; ++j) acc[r][j] = 0.0f;

    for (int k0 = 0; k0 < K; k0 += KC) {
        __syncthreads();
#pragma unroll
        for (int t = tid; t < 512; t += 256) {
            int r = t >> 3, c = t & 7;
            int row = n0 + r;
            row = row < N ? row : N - 1;
            float4 v = *(const float4*)&in[(long long)row * K + k0 + 4 * c];
            if (ACT) {
                int kk = k0 + 4 * c;
                v.x = fmaxf(fmaf(v.x, ss[kk + 0], ss[96 + kk + 0]), 0.0f);
                v.y = fmaxf(fmaf(v.y, ss[kk + 1], ss[96 + kk + 1]), 0.0f);
                v.z = fmaxf(fmaf(v.z, ss[kk + 2], ss[96 + kk + 2]), 0.0f);
                v.w = fmaxf(fmaf(v.w, ss[kk + 3], ss[96 + kk + 3]), 0.0f);
            }
            As[(4 * c + 0) * PITCH + r] = v.x;
            As[(4 * c + 1) * PITCH + r] = v.y;
            As[(4 * c + 2) * PITCH + r] = v.z;
            As[(4 * c + 3) * PITCH + r] = v.w;
        }
        __syncthreads();
#pragma unroll
        for (int k = 0; k < KC; ++k) {
            float4 a4 = *(const float4*)&As[k * PITCH + 4 * ty];
            const float* wr = &Wl[(k0 + k) * 96 + 6 * tx];   // FIX: global k index
            float w0 = wr[0], w1 = wr[1], w2 = wr[2], w3 = wr[3], w4 = wr[4], w5 = wr[5];
            float ar[4] = {a4.x, a4.y, a4.z, a4.w};
#pragma unroll
            for (int r = 0; r < 4; ++r) {
                acc[r][0] = fmaf(ar[r], w0, acc[r][0]);
                acc[r][1] = fmaf(ar[r], w1, acc[r][1]);
                acc[r][2] = fmaf(ar[r], w2, acc[r][2]);
                acc[r][3] = fmaf(ar[r], w3, acc[r][3]);
                acc[r][4] = fmaf(ar[r], w4, acc[r][4]);
                acc[r][5] = fmaf(ar[r], w5, acc[r][5]);
            }
        }
    }
    float bc[6];
#pragma unroll
    for (int j = 0; j < 6; ++j) bc[j] = BIAS ? bias[6 * tx + j] : 0.0f;
#pragma unroll
    for (int r = 0; r < 4; ++r) {
        int row = n0 + 4 * ty + r;
        if (row < N) {
#pragma unroll
            for (int j = 0; j < 6; ++j)
                out[(long long)row * 96 + 6 * tx + j] = acc[r][j] + bc[j];
        }
    }
}

// ---------------- final GEMM: out[N,64] = l2norm(act(in) @ Wp2 + bp2) -------

__global__ __launch_bounds__(256) void gemm_final(const float* __restrict__ in,
                                                  const float* __restrict__ W,
                                                  const float* __restrict__ bias,
                                                  const float* __restrict__ ss,
                                                  float* __restrict__ out, int N) {
    constexpr int K = 96, KC = 32, PITCH = 68;
    __shared__ float Wl[K * 64];
    __shared__ float As[KC * PITCH];
    __shared__ float rs[64];
    const int tid = threadIdx.x;
    for (int f = tid; f < K * 64 / 4; f += 256)
        ((float4*)Wl)[f] = ((const float4*)W)[f];
    const int n0 = blockIdx.x * 64;
    const int tx = tid & 15, ty = tid >> 4;
    float acc[4][4];
#pragma unroll
    for (int r = 0; r < 4; ++r)
#pragma unroll
        for (int j = 0; j < 4; ++j) acc[r][j] = bias[4 * tx + j];

    for (int k0 = 0; k0 < K; k0 += KC) {
        __syncthreads();
#pragma unroll
        for (int t = tid; t < 512; t += 256) {
            int r = t >> 3, c = t & 7;
            int row = n0 + r;
            row = row < N ? row : N - 1;
            float4 v = *(const float4*)&in[(long long)row * K + k0 + 4 * c];
            int kk = k0 + 4 * c;
            v.x = fmaxf(fmaf(v.x, ss[kk + 0], ss[96 + kk + 0]), 0.0f);
            v.y = fmaxf(fmaf(v.y, ss[kk + 1], ss[96 + kk + 1]), 0.0f);
            v.z = fmaxf(fmaf(v.z, ss[kk + 2], ss[96 + kk + 2]), 0.0f);
            v.w = fmaxf(fmaf(v.w, ss[kk + 3], ss[96 + kk + 3]), 0.0f);
            As[(4 * c + 0) * PITCH + r] = v.x;
            As[(4 * c + 1) * PITCH + r] = v.y;
            As[(4 * c + 2) * PITCH + r] = v.z;
            As[(4 * c + 3) * PITCH + r] = v.w;
        }
        __syncthreads();
#pragma unroll
        for (int k = 0; k < KC; ++k) {
            float4 a4 = *(const float4*)&As[k * PITCH + 4 * ty];
            float4 w4 = *(const float4*)&Wl[(k0 + k) * 64 + 4 * tx];  // FIX: global k index
            float ar[4] = {a4.x, a4.y, a4.z, a4.w};
#pragma unroll
            for (int r = 0; r < 4; ++r) {
                acc[r][0] = fmaf(ar[r], w4.x, acc[r][0]);
                acc[r][1] = fmaf(ar[r], w4.y, acc[r][1]);
                acc[r][2] = fmaf(ar[r], w4.z, acc[r][2]);
                acc[r][3] = fmaf(ar[r], w4.w, acc[r][3]);
            }
        }
    }
    // fused row L2 norm (bias already in acc)
    if (tid < 64) rs[tid] = 0.0f;
    __syncthreads();
#pragma unroll
    for (int r = 0; r < 4; ++r) {
        float p = acc[r][0] * acc[r][0] + acc[r][1] * acc[r][1] +
                  acc[r][2] * acc[r][2] + acc[r][3] * acc[r][3];
        atomicAdd(&rs[4 * ty + r], p);
    }
    __syncthreads();
#pragma unroll
    for (int r = 0; r < 4; ++r) {
        int row = n0 + 4 * ty + r;
        if (row < N) {
            float sc = 1.0f / fmaxf(sqrtf(rs[4 * ty + r]), 1e-12f);
            float4 o;
            o.x = acc[r][0] * sc; o.y = acc[r][1] * sc;
            o.z = acc[r][2] * sc; o.w = acc[r][3] * sc;
            *(float4*)&out[(long long)row * 64 + 4 * tx] = o;
        }
    }
}

// ---------------- CSR pull aggregation + fused BN stats ----------------
// out[n] = bias + dis[n]^2 * xw[n] + sum_e nrm_e * xw[src_e]; thread = (n, 4-col grp)

__global__ __launch_bounds__(256) void agg96(const float* __restrict__ xw,
                                             const int* __restrict__ rowptr,
                                             const int* __restrict__ csrc,
                                             const float* __restrict__ cnrm,
                                             const float* __restrict__ dis,
                                             const float* __restrict__ bias,
                                             float* __restrict__ out,
                                             float* __restrict__ sums, int N) {
    __shared__ float sb[192];
    const int tid = threadIdx.x;
    if (tid < 192) sb[tid] = 0.0f;
    __syncthreads();
    int idx = blockIdx.x * 256 + tid;
    if (idx < N * 24) {
        int n = idx / 24, c4 = idx % 24;
        float d = dis[n];
        float4 xv = *(const float4*)&xw[n * 96 + 4 * c4];
        float4 acc;
        acc.x = fmaf(xv.x, d * d, bias[4 * c4 + 0]);
        acc.y = fmaf(xv.y, d * d, bias[4 * c4 + 1]);
        acc.z = fmaf(xv.z, d * d, bias[4 * c4 + 2]);
        acc.w = fmaf(xv.w, d * d, bias[4 * c4 + 3]);
        int e = rowptr[n], e1 = rowptr[n + 1];
        for (; e + 1 < e1; e += 2) {
            int s0 = csrc[e], s1 = csrc[e + 1];
            float w0 = cnrm[e], w1 = cnrm[e + 1];
            float4 v0 = *(const float4*)&xw[s0 * 96 + 4 * c4];
            float4 v1 = *(const float4*)&xw[s1 * 96 + 4 * c4];
            acc.x = fmaf(v0.x, w0, acc.x); acc.y = fmaf(v0.y, w0, acc.y);
            acc.z = fmaf(v0.z, w0, acc.z); acc.w = fmaf(v0.w, w0, acc.w);
            acc.x = fmaf(v1.x, w1, acc.x); acc.y = fmaf(v1.y, w1, acc.y);
            acc.z = fmaf(v1.z, w1, acc.z); acc.w = fmaf(v1.w, w1, acc.w);
        }
        if (e < e1) {
            int s0 = csrc[e];
            float w0 = cnrm[e];
            float4 v0 = *(const float4*)&xw[s0 * 96 + 4 * c4];
            acc.x = fmaf(v0.x, w0, acc.x); acc.y = fmaf(v0.y, w0, acc.y);
            acc.z = fmaf(v0.z, w0, acc.z); acc.w = fmaf(v0.w, w0, acc.w);
        }
        *(float4*)&out[n * 96 + 4 * c4] = acc;
        atomicAdd(&sb[4 * c4 + 0], acc.x);
        atomicAdd(&sb[4 * c4 + 1], acc.y);
        atomicAdd(&sb[4 * c4 + 2], acc.z);
        atomicAdd(&sb[4 * c4 + 3], acc.w);
        atomicAdd(&sb[96 + 4 * c4 + 0], acc.x * acc.x);
        atomicAdd(&sb[96 + 4 * c4 + 1], acc.y * acc.y);
        atomicAdd(&sb[96 + 4 * c4 + 2], acc.z * acc.z);
        atomicAdd(&sb[96 + 4 * c4 + 3], acc.w * acc.w);
    }
    __syncthreads();
    if (tid < 192) atomicAdd(&sums[tid], sb[tid]);
}

// ---------------- standalone BN stats (for projector) ----------------

__global__ __launch_bounds__(256) void bn_stats96(const float* __restrict__ h,
                                                  float* __restrict__ sums, int N) {
    __shared__ float sb[192];
    const int tid = threadIdx.x;
    if (tid < 192) sb[tid] = 0.0f;
    __syncthreads();
    int g = blockIdx.x * 256 + tid;
    int total = N * 24, stride = gridDim.x * 256;  // stride multiple of 24
    float4 s4 = {0, 0, 0, 0}, q4 = {0, 0, 0, 0};
    int c4 = g % 24;
    for (int i = g; i < total; i += stride) {
        int n = i / 24;
        float4 v = *(const float4*)&h[n * 96 + 4 * c4];
        s4.x += v.x; s4.y += v.y; s4.z += v.z; s4.w += v.w;
        q4.x += v.x * v.x; q4.y += v.y * v.y; q4.z += v.z * v.z; q4.w += v.w * v.w;
    }
    atomicAdd(&sb[4 * c4 + 0], s4.x);
    atomicAdd(&sb[4 * c4 + 1], s4.y);
    atomicAdd(&sb[4 * c4 + 2], s4.z);
    atomicAdd(&sb[4 * c4 + 3], s4.w);
    atomicAdd(&sb[96 + 4 * c4 + 0], q4.x);
    atomicAdd(&sb[96 + 4 * c4 + 1], q4.y);
    atomicAdd(&sb[96 + 4 * c4 + 2], q4.z);
    atomicAdd(&sb[96 + 4 * c4 + 3], q4.w);
    __syncthreads();
    if (tid < 192) atomicAdd(&sums[tid], sb[tid]);
}

__global__ void bn_finalize96(const float* __restrict__ sums, const float* __restrict__ gamma,
                              const float* __restrict__ beta, float* __restrict__ ss, int N) {
    int i = threadIdx.x;
    if (i < 96) {
        float inv_n = 1.0f / (float)N;
        float mean = sums[i] * inv_n;
        float var = sums[96 + i] * inv_n - mean * mean;
        float sc = gamma[i] * rsqrtf(var + 1e-5f);
        ss[i] = sc;
        ss[96 + i] = beta[i] - mean * sc;
    }
}

// ---------------- launch ----------------

extern "C" void kernel_launch(void* const* d_in, const int* in_sizes, int n_in,
                              void* d_out, int out_size, void* d_ws, size_t ws_size,
                              hipStream_t stream) {
    const float* x   = (const float*)d_in[0];
    const int*   ei  = (const int*)d_in[1];
    const float* W1  = (const float*)d_in[2];
    const float* b1  = (const float*)d_in[3];
    const float* g1  = (const float*)d_in[4];
    const float* be1 = (const float*)d_in[5];
    const float* W2  = (const float*)d_in[6];
    const float* b2  = (const float*)d_in[7];
    const float* g2  = (const float*)d_in[8];
    const float* be2 = (const float*)d_in[9];
    const float* Wp1 = (const float*)d_in[10];
    const float* bp1 = (const float*)d_in[11];
    const float* gp  = (const float*)d_in[12];
    const float* bep = (const float*)d_in[13];
    const float* Wp2 = (const float*)d_in[14];
    const float* bp2 = (const float*)d_in[15];

    const int N = in_sizes[0] / 128;   // 50000
    const int E = in_sizes[1] / 2;     // 800000
    const int* src = ei;
    const int* dst = ei + E;

    // workspace layout
    char* w = (char*)d_ws;
    auto alloc = [&](size_t bytes) { char* p = w; w += (bytes + 15) & ~size_t(15); return p; };
    int*   cnt    = (int*)alloc((size_t)N * 4);
    int*   rowptr = (int*)alloc((size_t)(N + 1) * 4);
    int*   bsum   = (int*)alloc(64 * 4);
    int*   boff   = (int*)alloc(64 * 4);
    float* dis    = (float*)alloc((size_t)N * 4);
    int*   csrc   = (int*)alloc((size_t)E * 4);
    float* cnrm   = (float*)alloc((size_t)E * 4);
    float* buf1   = (float*)alloc((size_t)N * 96 * 4);
    float* buf2   = (float*)alloc((size_t)N * 96 * 4);
    float* sums   = (float*)alloc(576 * 4);   // 3 x 192
    float* ss     = (float*)alloc(576 * 4);   // 3 x 192
    float* sums1 = sums, *sums2 = sums + 192, *sums3 = sums + 384;
    float* ss1 = ss, *ss2 = ss + 192, *ss3 = ss + 384;

    float* out = (float*)d_out;

    const int gE = cdiv(E, BLK);
    const int gG = cdiv(N, 64);          // 782 gemm blocks
    const int gA = cdiv((long long)N * 24, BLK);  // 4688 agg blocks
    const int nb = cdiv(N, 1024);        // scan blocks (49)

    // CSR build
    zero_int<<<cdiv(N, BLK), BLK, 0, stream>>>(cnt, N);
    count_dst<<<gE, BLK, 0, stream>>>(dst, cnt, E);
    dis_k<<<cdiv(N, BLK), BLK, 0, stream>>>(cnt, dis, N);
    scan1<<<nb, 256, 0, stream>>>(cnt, rowptr, bsum, N);
    scan2<<<1, 64, 0, stream>>>(bsum, boff, nb);
    scan3<<<cdiv(N, BLK), BLK, 0, stream>>>(rowptr, boff, N, E);
    zero_int<<<cdiv(N, BLK), BLK, 0, stream>>>(cnt, N);
    csr_fill<<<gE, BLK, 0, stream>>>(src, dst, rowptr, cnt, dis, csrc, cnrm, E);
    zero_f<<<1, 576, 0, stream>>>(sums, 576);

    // layer 1
    gemm96<128, false, false><<<gG, 256, 0, stream>>>(x, W1, nullptr, nullptr, buf1, N);
    agg96<<<gA, 256, 0, stream>>>(buf1, rowptr, csrc, cnrm, dis, b1, buf2, sums1, N);
    bn_finalize96<<<1, 128, 0, stream>>>(sums1, g1, be1, ss1, N);

    // layer 2 (BN+ReLU of layer 1 fused into A staging)
    gemm96<96, true, false><<<gG, 256, 0, stream>>>(buf2, W2, nullptr, ss1, buf1, N);
    agg96<<<gA, 256, 0, stream>>>(buf1, rowptr, csrc, cnrm, dis, b2, buf2, sums2, N);
    bn_finalize96<<<1, 128, 0, stream>>>(sums2, g2, be2, ss2, N);

    // projector linear 1 (BN+ReLU of layer 2 fused)
    gemm96<96, true, true><<<gG, 256, 0, stream>>>(buf2, Wp1, bp1, ss2, buf1, N);
    bn_stats96<<<960, 256, 0, stream>>>(buf1, sums3, N);
    bn_finalize96<<<1, 128, 0, stream>>>(sums3, gp, bep, ss3, N);

    // projector linear 2 + fused L2 normalize (BN+ReLU fused)
    gemm_final<<<gG, 256, 0, stream>>>(buf1, Wp2, bp2, ss3, out, N);
}

// Round 5
// 496.136 us; speedup vs baseline: 2.7685x; 1.5026x over previous
//
#include <hip/hip_runtime.h>
#include <hip/hip_fp16.h>

constexpr int BLK = 256;

static inline int cdiv(long long a, int b) { return (int)((a + b - 1) / b); }

struct Edge { int s; float w; };  // 8 B, array base 16B-aligned -> always 8B-aligned

// ---------------- utility ----------------

__global__ void zero_int(int* __restrict__ p, int n) {
    for (int i = blockIdx.x * blockDim.x + threadIdx.x; i < n; i += gridDim.x * blockDim.x)
        p[i] = 0;
}

__global__ void zero_f(float* __restrict__ p, int n) {
    for (int i = blockIdx.x * blockDim.x + threadIdx.x; i < n; i += gridDim.x * blockDim.x)
        p[i] = 0.0f;
}

// ---------------- degree / CSR build ----------------

__global__ void count_dst(const int* __restrict__ dst, int* __restrict__ cnt, int E) {
    for (int i = blockIdx.x * blockDim.x + threadIdx.x; i < E; i += gridDim.x * blockDim.x)
        atomicAdd(&cnt[dst[i]], 1);
}

__global__ void dis_k(const int* __restrict__ cnt, float* __restrict__ dis, int N) {
    for (int i = blockIdx.x * blockDim.x + threadIdx.x; i < N; i += gridDim.x * blockDim.x)
        dis[i] = rsqrtf((float)cnt[i] + 1.0f);  // +1 self-loop
}

// block scans 1024 elements (256 threads x 4)
__global__ void scan1(const int* __restrict__ cnt, int* __restrict__ rowptr,
                      int* __restrict__ bsum, int N) {
    __shared__ int ts[256];
    int tid = threadIdx.x;
    int base = blockIdx.x * 1024 + tid * 4;
    int v[4], s = 0;
#pragma unroll
    for (int i = 0; i < 4; ++i) {
        v[i] = (base + i < N) ? cnt[base + i] : 0;
        s += v[i];
    }
    ts[tid] = s;
    __syncthreads();
    for (int off = 1; off < 256; off <<= 1) {
        int t = 0;
        if (tid >= off) t = ts[tid - off];
        __syncthreads();
        if (tid >= off) ts[tid] += t;
        __syncthreads();
    }
    int run = ts[tid] - s;
#pragma unroll
    for (int i = 0; i < 4; ++i) {
        if (base + i < N) rowptr[base + i] = run;
        run += v[i];
    }
    if (tid == 255) bsum[blockIdx.x] = ts[255];
}

__global__ void scan2(const int* __restrict__ bsum, int* __restrict__ boff, int nb) {
    if (threadIdx.x == 0) {
        int r = 0;
        for (int i = 0; i < nb; ++i) { boff[i] = r; r += bsum[i]; }
    }
}

__global__ void scan3(int* __restrict__ rowptr, const int* __restrict__ boff, int N, int E) {
    int i = blockIdx.x * blockDim.x + threadIdx.x;
    if (i < N) rowptr[i] += boff[i >> 10];
    if (i == 0) rowptr[N] = E;
}

__global__ void csr_fill(const int* __restrict__ src, const int* __restrict__ dst,
                         const int* __restrict__ rowptr, int* __restrict__ cur,
                         const float* __restrict__ dis, Edge* __restrict__ edges, int E) {
    for (int i = blockIdx.x * blockDim.x + threadIdx.x; i < E; i += gridDim.x * blockDim.x) {
        int s = src[i], d = dst[i];
        int slot = rowptr[d] + atomicAdd(&cur[d], 1);
        Edge e; e.s = s; e.w = dis[s] * dis[d];
        edges[slot] = e;
    }
}

// ---------------- tiled GEMM: out[N,96] = act(in)[N,K] @ W[K,96] (+bias) ----
// act = relu(x*ss[k] + ss[96+k]) when ACT. Block: 64 rows x 96 cols, thread 4x6.
// HOUT: also write fp16 shadow copy for the gather path.

template <int K, bool ACT, bool BIAS, bool HOUT>
__global__ __launch_bounds__(256) void gemm96(const float* __restrict__ in,
                                              const float* __restrict__ W,
                                              const float* __restrict__ bias,
                                              const float* __restrict__ ss,
                                              float* __restrict__ out,
                                              __half* __restrict__ hout, int N) {
    constexpr int KC = 32, PITCH = 68;
    __shared__ float Wl[K * 96];
    __shared__ float As[KC * PITCH];
    const int tid = threadIdx.x;
    for (int f = tid; f < K * 96 / 4; f += 256)
        ((float4*)Wl)[f] = ((const float4*)W)[f];
    const int n0 = blockIdx.x * 64;
    const int tx = tid & 15, ty = tid >> 4;
    float acc[4][6];
#pragma unroll
    for (int r = 0; r < 4; ++r)
#pragma unroll
        for (int j = 0; j < 6; ++j) acc[r][j] = 0.0f;

    for (int k0 = 0; k0 < K; k0 += KC) {
        __syncthreads();
#pragma unroll
        for (int t = tid; t < 512; t += 256) {
            int r = t >> 3, c = t & 7;
            int row = n0 + r;
            row = row < N ? row : N - 1;
            float4 v = *(const float4*)&in[(long long)row * K + k0 + 4 * c];
            if (ACT) {
                int kk = k0 + 4 * c;
                v.x = fmaxf(fmaf(v.x, ss[kk + 0], ss[96 + kk + 0]), 0.0f);
                v.y = fmaxf(fmaf(v.y, ss[kk + 1], ss[96 + kk + 1]), 0.0f);
                v.z = fmaxf(fmaf(v.z, ss[kk + 2], ss[96 + kk + 2]), 0.0f);
                v.w = fmaxf(fmaf(v.w, ss[kk + 3], ss[96 + kk + 3]), 0.0f);
            }
            As[(4 * c + 0) * PITCH + r] = v.x;
            As[(4 * c + 1) * PITCH + r] = v.y;
            As[(4 * c + 2) * PITCH + r] = v.z;
            As[(4 * c + 3) * PITCH + r] = v.w;
        }
        __syncthreads();
#pragma unroll
        for (int k = 0; k < KC; ++k) {
            float4 a4 = *(const float4*)&As[k * PITCH + 4 * ty];
            const float* wr = &Wl[(k0 + k) * 96 + 6 * tx];
            float w0 = wr[0], w1 = wr[1], w2 = wr[2], w3 = wr[3], w4 = wr[4], w5 = wr[5];
            float ar[4] = {a4.x, a4.y, a4.z, a4.w};
#pragma unroll
            for (int r = 0; r < 4; ++r) {
                acc[r][0] = fmaf(ar[r], w0, acc[r][0]);
                acc[r][1] = fmaf(ar[r], w1, acc[r][1]);
                acc[r][2] = fmaf(ar[r], w2, acc[r][2]);
                acc[r][3] = fmaf(ar[r], w3, acc[r][3]);
                acc[r][4] = fmaf(ar[r], w4, acc[r][4]);
                acc[r][5] = fmaf(ar[r], w5, acc[r][5]);
            }
        }
    }
    float bc[6];
#pragma unroll
    for (int j = 0; j < 6; ++j) bc[j] = BIAS ? bias[6 * tx + j] : 0.0f;
#pragma unroll
    for (int r = 0; r < 4; ++r) {
        int row = n0 + 4 * ty + r;
        if (row < N) {
            float o[6];
#pragma unroll
            for (int j = 0; j < 6; ++j) {
                o[j] = acc[r][j] + bc[j];
                out[(long long)row * 96 + 6 * tx + j] = o[j];
            }
            if (HOUT) {
#pragma unroll
                for (int j = 0; j < 6; j += 2) {
                    __half2 h2 = __floats2half2_rn(o[j], o[j + 1]);
                    *(__half2*)&hout[(long long)row * 96 + 6 * tx + j] = h2;
                }
            }
        }
    }
}

// ---------------- final GEMM: out[N,64] = l2norm(act(in) @ Wp2 + bp2) -------

__global__ __launch_bounds__(256) void gemm_final(const float* __restrict__ in,
                                                  const float* __restrict__ W,
                                                  const float* __restrict__ bias,
                                                  const float* __restrict__ ss,
                                                  float* __restrict__ out, int N) {
    constexpr int K = 96, KC = 32, PITCH = 68;
    __shared__ float Wl[K * 64];
    __shared__ float As[KC * PITCH];
    __shared__ float rs[64];
    const int tid = threadIdx.x;
    for (int f = tid; f < K * 64 / 4; f += 256)
        ((float4*)Wl)[f] = ((const float4*)W)[f];
    const int n0 = blockIdx.x * 64;
    const int tx = tid & 15, ty = tid >> 4;
    float acc[4][4];
#pragma unroll
    for (int r = 0; r < 4; ++r)
#pragma unroll
        for (int j = 0; j < 4; ++j) acc[r][j] = bias[4 * tx + j];

    for (int k0 = 0; k0 < K; k0 += KC) {
        __syncthreads();
#pragma unroll
        for (int t = tid; t < 512; t += 256) {
            int r = t >> 3, c = t & 7;
            int row = n0 + r;
            row = row < N ? row : N - 1;
            float4 v = *(const float4*)&in[(long long)row * K + k0 + 4 * c];
            int kk = k0 + 4 * c;
            v.x = fmaxf(fmaf(v.x, ss[kk + 0], ss[96 + kk + 0]), 0.0f);
            v.y = fmaxf(fmaf(v.y, ss[kk + 1], ss[96 + kk + 1]), 0.0f);
            v.z = fmaxf(fmaf(v.z, ss[kk + 2], ss[96 + kk + 2]), 0.0f);
            v.w = fmaxf(fmaf(v.w, ss[kk + 3], ss[96 + kk + 3]), 0.0f);
            As[(4 * c + 0) * PITCH + r] = v.x;
            As[(4 * c + 1) * PITCH + r] = v.y;
            As[(4 * c + 2) * PITCH + r] = v.z;
            As[(4 * c + 3) * PITCH + r] = v.w;
        }
        __syncthreads();
#pragma unroll
        for (int k = 0; k < KC; ++k) {
            float4 a4 = *(const float4*)&As[k * PITCH + 4 * ty];
            float4 w4 = *(const float4*)&Wl[(k0 + k) * 64 + 4 * tx];
            float ar[4] = {a4.x, a4.y, a4.z, a4.w};
#pragma unroll
            for (int r = 0; r < 4; ++r) {
                acc[r][0] = fmaf(ar[r], w4.x, acc[r][0]);
                acc[r][1] = fmaf(ar[r], w4.y, acc[r][1]);
                acc[r][2] = fmaf(ar[r], w4.z, acc[r][2]);
                acc[r][3] = fmaf(ar[r], w4.w, acc[r][3]);
            }
        }
    }
    if (tid < 64) rs[tid] = 0.0f;
    __syncthreads();
#pragma unroll
    for (int r = 0; r < 4; ++r) {
        float p = acc[r][0] * acc[r][0] + acc[r][1] * acc[r][1] +
                  acc[r][2] * acc[r][2] + acc[r][3] * acc[r][3];
        atomicAdd(&rs[4 * ty + r], p);
    }
    __syncthreads();
#pragma unroll
    for (int r = 0; r < 4; ++r) {
        int row = n0 + 4 * ty + r;
        if (row < N) {
            float sc = 1.0f / fmaxf(sqrtf(rs[4 * ty + r]), 1e-12f);
            float4 o;
            o.x = acc[r][0] * sc; o.y = acc[r][1] * sc;
            o.z = acc[r][2] * sc; o.w = acc[r][3] * sc;
            *(float4*)&out[(long long)row * 64 + 4 * tx] = o;
        }
    }
}

// ---------------- CSR pull aggregation (fp16 gather path) ----------------
// out[n] = bias + dis[n]^2 * xw[n] + sum_e w_e * hxw[src_e]
// 12 threads per node, 8 cols (16 B fp16) each, edge loop unrolled x4.

__global__ __launch_bounds__(256) void agg96h(const float* __restrict__ xw,
                                              const __half* __restrict__ hxw,
                                              const int* __restrict__ rowptr,
                                              const Edge* __restrict__ edges,
                                              const float* __restrict__ dis,
                                              const float* __restrict__ bias,
                                              float* __restrict__ out, int N) {
    int idx = blockIdx.x * 256 + threadIdx.x;
    if (idx >= N * 12) return;
    int n = idx / 12, c8 = idx % 12;
    float d = dis[n];
    float dd = d * d;
    float acc[8];
    {
        const float4 x0 = *(const float4*)&xw[n * 96 + c8 * 8];
        const float4 x1 = *(const float4*)&xw[n * 96 + c8 * 8 + 4];
        acc[0] = fmaf(x0.x, dd, bias[c8 * 8 + 0]);
        acc[1] = fmaf(x0.y, dd, bias[c8 * 8 + 1]);
        acc[2] = fmaf(x0.z, dd, bias[c8 * 8 + 2]);
        acc[3] = fmaf(x0.w, dd, bias[c8 * 8 + 3]);
        acc[4] = fmaf(x1.x, dd, bias[c8 * 8 + 4]);
        acc[5] = fmaf(x1.y, dd, bias[c8 * 8 + 5]);
        acc[6] = fmaf(x1.z, dd, bias[c8 * 8 + 6]);
        acc[7] = fmaf(x1.w, dd, bias[c8 * 8 + 7]);
    }
    int e = rowptr[n], e1 = rowptr[n + 1];
    for (; e + 3 < e1; e += 4) {
        Edge E0 = edges[e], E1 = edges[e + 1], E2 = edges[e + 2], E3 = edges[e + 3];
        float4 g0 = *(const float4*)&hxw[E0.s * 96 + c8 * 8];
        float4 g1 = *(const float4*)&hxw[E1.s * 96 + c8 * 8];
        float4 g2 = *(const float4*)&hxw[E2.s * 96 + c8 * 8];
        float4 g3 = *(const float4*)&hxw[E3.s * 96 + c8 * 8];
        const __half2* h0 = (const __half2*)&g0;
        const __half2* h1 = (const __half2*)&g1;
        const __half2* h2 = (const __half2*)&g2;
        const __half2* h3 = (const __half2*)&g3;
#pragma unroll
        for (int k = 0; k < 4; ++k) {
            float2 f0 = __half22float2(h0[k]);
            float2 f1 = __half22float2(h1[k]);
            float2 f2 = __half22float2(h2[k]);
            float2 f3 = __half22float2(h3[k]);
            acc[2 * k + 0] = fmaf(f0.x, E0.w, acc[2 * k + 0]);
            acc[2 * k + 1] = fmaf(f0.y, E0.w, acc[2 * k + 1]);
            acc[2 * k + 0] = fmaf(f1.x, E1.w, acc[2 * k + 0]);
            acc[2 * k + 1] = fmaf(f1.y, E1.w, acc[2 * k + 1]);
            acc[2 * k + 0] = fmaf(f2.x, E2.w, acc[2 * k + 0]);
            acc[2 * k + 1] = fmaf(f2.y, E2.w, acc[2 * k + 1]);
            acc[2 * k + 0] = fmaf(f3.x, E3.w, acc[2 * k + 0]);
            acc[2 * k + 1] = fmaf(f3.y, E3.w, acc[2 * k + 1]);
        }
    }
    for (; e < e1; ++e) {
        Edge E0 = edges[e];
        float4 g0 = *(const float4*)&hxw[E0.s * 96 + c8 * 8];
        const __half2* h0 = (const __half2*)&g0;
#pragma unroll
        for (int k = 0; k < 4; ++k) {
            float2 f0 = __half22float2(h0[k]);
            acc[2 * k + 0] = fmaf(f0.x, E0.w, acc[2 * k + 0]);
            acc[2 * k + 1] = fmaf(f0.y, E0.w, acc[2 * k + 1]);
        }
    }
    float4 o0, o1;
    o0.x = acc[0]; o0.y = acc[1]; o0.z = acc[2]; o0.w = acc[3];
    o1.x = acc[4]; o1.y = acc[5]; o1.z = acc[6]; o1.w = acc[7];
    *(float4*)&out[n * 96 + c8 * 8] = o0;
    *(float4*)&out[n * 96 + c8 * 8 + 4] = o1;
}

// ---------------- BN stats (coalesced grid-stride) ----------------

__global__ __launch_bounds__(256) void bn_stats96(const float* __restrict__ h,
                                                  float* __restrict__ sums, int N) {
    __shared__ float sb[192];
    const int tid = threadIdx.x;
    if (tid < 192) sb[tid] = 0.0f;
    __syncthreads();
    int g = blockIdx.x * 256 + tid;
    int total = N * 24, stride = gridDim.x * 256;  // stride multiple of 24
    float4 s4 = {0, 0, 0, 0}, q4 = {0, 0, 0, 0};
    int c4 = g % 24;
    for (int i = g; i < total; i += stride) {
        int n = i / 24;
        float4 v = *(const float4*)&h[n * 96 + 4 * c4];
        s4.x += v.x; s4.y += v.y; s4.z += v.z; s4.w += v.w;
        q4.x += v.x * v.x; q4.y += v.y * v.y; q4.z += v.z * v.z; q4.w += v.w * v.w;
    }
    atomicAdd(&sb[4 * c4 + 0], s4.x);
    atomicAdd(&sb[4 * c4 + 1], s4.y);
    atomicAdd(&sb[4 * c4 + 2], s4.z);
    atomicAdd(&sb[4 * c4 + 3], s4.w);
    atomicAdd(&sb[96 + 4 * c4 + 0], q4.x);
    atomicAdd(&sb[96 + 4 * c4 + 1], q4.y);
    atomicAdd(&sb[96 + 4 * c4 + 2], q4.z);
    atomicAdd(&sb[96 + 4 * c4 + 3], q4.w);
    __syncthreads();
    if (tid < 192) atomicAdd(&sums[tid], sb[tid]);
}

__global__ void bn_finalize96(const float* __restrict__ sums, const float* __restrict__ gamma,
                              const float* __restrict__ beta, float* __restrict__ ss, int N) {
    int i = threadIdx.x;
    if (i < 96) {
        float inv_n = 1.0f / (float)N;
        float mean = sums[i] * inv_n;
        float var = sums[96 + i] * inv_n - mean * mean;
        float sc = gamma[i] * rsqrtf(var + 1e-5f);
        ss[i] = sc;
        ss[96 + i] = beta[i] - mean * sc;
    }
}

// ---------------- launch ----------------

extern "C" void kernel_launch(void* const* d_in, const int* in_sizes, int n_in,
                              void* d_out, int out_size, void* d_ws, size_t ws_size,
                              hipStream_t stream) {
    const float* x   = (const float*)d_in[0];
    const int*   ei  = (const int*)d_in[1];
    const float* W1  = (const float*)d_in[2];
    const float* b1  = (const float*)d_in[3];
    const float* g1  = (const float*)d_in[4];
    const float* be1 = (const float*)d_in[5];
    const float* W2  = (const float*)d_in[6];
    const float* b2  = (const float*)d_in[7];
    const float* g2  = (const float*)d_in[8];
    const float* be2 = (const float*)d_in[9];
    const float* Wp1 = (const float*)d_in[10];
    const float* bp1 = (const float*)d_in[11];
    const float* gp  = (const float*)d_in[12];
    const float* bep = (const float*)d_in[13];
    const float* Wp2 = (const float*)d_in[14];
    const float* bp2 = (const float*)d_in[15];

    const int N = in_sizes[0] / 128;   // 50000
    const int E = in_sizes[1] / 2;     // 800000
    const int* src = ei;
    const int* dst = ei + E;

    // workspace layout (~55 MB)
    char* w = (char*)d_ws;
    auto alloc = [&](size_t bytes) { char* p = w; w += (bytes + 15) & ~size_t(15); return p; };
    int*    cnt    = (int*)alloc((size_t)N * 4);
    int*    rowptr = (int*)alloc((size_t)(N + 1) * 4);
    int*    bsum   = (int*)alloc(64 * 4);
    int*    boff   = (int*)alloc(64 * 4);
    float*  dis    = (float*)alloc((size_t)N * 4);
    Edge*   edges  = (Edge*)alloc((size_t)E * 8);
    float*  buf1   = (float*)alloc((size_t)N * 96 * 4);
    float*  buf2   = (float*)alloc((size_t)N * 96 * 4);
    __half* hbuf   = (__half*)alloc((size_t)N * 96 * 2);
    float*  sums   = (float*)alloc(576 * 4);
    float*  ss     = (float*)alloc(576 * 4);
    float* sums1 = sums, *sums2 = sums + 192, *sums3 = sums + 384;
    float* ss1 = ss, *ss2 = ss + 192, *ss3 = ss + 384;

    float* out = (float*)d_out;

    const int gE = cdiv(E, BLK);
    const int gG = cdiv(N, 64);                    // 782 gemm blocks
    const int gA = cdiv((long long)N * 12, BLK);   // 2344 agg blocks
    const int nb = cdiv(N, 1024);                  // scan blocks (49)

    // CSR build
    zero_int<<<cdiv(N, BLK), BLK, 0, stream>>>(cnt, N);
    count_dst<<<gE, BLK, 0, stream>>>(dst, cnt, E);
    dis_k<<<cdiv(N, BLK), BLK, 0, stream>>>(cnt, dis, N);
    scan1<<<nb, 256, 0, stream>>>(cnt, rowptr, bsum, N);
    scan2<<<1, 64, 0, stream>>>(bsum, boff, nb);
    scan3<<<cdiv(N, BLK), BLK, 0, stream>>>(rowptr, boff, N, E);
    zero_int<<<cdiv(N, BLK), BLK, 0, stream>>>(cnt, N);
    csr_fill<<<gE, BLK, 0, stream>>>(src, dst, rowptr, cnt, dis, edges, E);
    zero_f<<<1, 576, 0, stream>>>(sums, 576);

    // layer 1
    gemm96<128, false, false, true><<<gG, 256, 0, stream>>>(x, W1, nullptr, nullptr, buf1, hbuf, N);
    agg96h<<<gA, 256, 0, stream>>>(buf1, hbuf, rowptr, edges, dis, b1, buf2, N);
    bn_stats96<<<960, 256, 0, stream>>>(buf2, sums1, N);
    bn_finalize96<<<1, 128, 0, stream>>>(sums1, g1, be1, ss1, N);

    // layer 2 (BN+ReLU of layer 1 fused into A staging)
    gemm96<96, true, false, true><<<gG, 256, 0, stream>>>(buf2, W2, nullptr, ss1, buf1, hbuf, N);
    agg96h<<<gA, 256, 0, stream>>>(buf1, hbuf, rowptr, edges, dis, b2, buf2, N);
    bn_stats96<<<960, 256, 0, stream>>>(buf2, sums2, N);
    bn_finalize96<<<1, 128, 0, stream>>>(sums2, g2, be2, ss2, N);

    // projector linear 1 (BN+ReLU of layer 2 fused)
    gemm96<96, true, true, false><<<gG, 256, 0, stream>>>(buf2, Wp1, bp1, ss2, buf1, nullptr, N);
    bn_stats96<<<960, 256, 0, stream>>>(buf1, sums3, N);
    bn_finalize96<<<1, 128, 0, stream>>>(sums3, gp, bep, ss3, N);

    // projector linear 2 + fused L2 normalize (BN+ReLU fused)
    gemm_final<<<gG, 256, 0, stream>>>(buf1, Wp2, bp2, ss3, out, N);
}

// Round 6
// 490.747 us; speedup vs baseline: 2.7989x; 1.0110x over previous
//
#include <hip/hip_runtime.h>
#include <hip/hip_fp16.h>

constexpr int BLK = 256;

static inline int cdiv(long long a, int b) { return (int)((a + b - 1) / b); }

struct Edge { int s; float w; };  // 8 B

// ---------------- utility ----------------

__global__ void zero_int(int* __restrict__ p, int n) {
    for (int i = blockIdx.x * blockDim.x + threadIdx.x; i < n; i += gridDim.x * blockDim.x)
        p[i] = 0;
}

__global__ void zero_f(float* __restrict__ p, int n) {
    for (int i = blockIdx.x * blockDim.x + threadIdx.x; i < n; i += gridDim.x * blockDim.x)
        p[i] = 0.0f;
}

// ---------------- degree / CSR build ----------------

__global__ void count_dst(const int* __restrict__ dst, int* __restrict__ cnt, int E) {
    int i0 = (blockIdx.x * blockDim.x + threadIdx.x) * 4;
    if (i0 + 3 < E) {
        int d0 = dst[i0], d1 = dst[i0 + 1], d2 = dst[i0 + 2], d3 = dst[i0 + 3];
        atomicAdd(&cnt[d0], 1);
        atomicAdd(&cnt[d1], 1);
        atomicAdd(&cnt[d2], 1);
        atomicAdd(&cnt[d3], 1);
    } else {
        for (int i = i0; i < E; ++i) atomicAdd(&cnt[dst[i]], 1);
    }
}

__global__ void dis_k(const int* __restrict__ cnt, float* __restrict__ dis, int N) {
    for (int i = blockIdx.x * blockDim.x + threadIdx.x; i < N; i += gridDim.x * blockDim.x)
        dis[i] = rsqrtf((float)cnt[i] + 1.0f);  // +1 self-loop
}

// block scans 1024 elements (256 threads x 4)
__global__ void scan1(const int* __restrict__ cnt, int* __restrict__ rowptr,
                      int* __restrict__ bsum, int N) {
    __shared__ int ts[256];
    int tid = threadIdx.x;
    int base = blockIdx.x * 1024 + tid * 4;
    int v[4], s = 0;
#pragma unroll
    for (int i = 0; i < 4; ++i) {
        v[i] = (base + i < N) ? cnt[base + i] : 0;
        s += v[i];
    }
    ts[tid] = s;
    __syncthreads();
    for (int off = 1; off < 256; off <<= 1) {
        int t = 0;
        if (tid >= off) t = ts[tid - off];
        __syncthreads();
        if (tid >= off) ts[tid] += t;
        __syncthreads();
    }
    int run = ts[tid] - s;
#pragma unroll
    for (int i = 0; i < 4; ++i) {
        if (base + i < N) rowptr[base + i] = run;
        run += v[i];
    }
    if (tid == 255) bsum[blockIdx.x] = ts[255];
}

__global__ void scan2(const int* __restrict__ bsum, int* __restrict__ boff, int nb) {
    if (threadIdx.x == 0) {
        int r = 0;
        for (int i = 0; i < nb; ++i) { boff[i] = r; r += bsum[i]; }
    }
}

__global__ void scan3(int* __restrict__ rowptr, const int* __restrict__ boff, int N, int E) {
    int i = blockIdx.x * blockDim.x + threadIdx.x;
    if (i < N) rowptr[i] += boff[i >> 10];
    if (i == 0) rowptr[N] = E;
}

// 4 independent gather/atomic/store chains per thread for MLP
__global__ void csr_fill(const int* __restrict__ src, const int* __restrict__ dst,
                         const int* __restrict__ rowptr, int* __restrict__ cur,
                         const float* __restrict__ dis, Edge* __restrict__ edges, int E) {
    int i0 = (blockIdx.x * blockDim.x + threadIdx.x) * 4;
    if (i0 + 3 < E) {
        int s0 = src[i0], s1 = src[i0 + 1], s2 = src[i0 + 2], s3 = src[i0 + 3];
        int d0 = dst[i0], d1 = dst[i0 + 1], d2 = dst[i0 + 2], d3 = dst[i0 + 3];
        float a0 = dis[s0], a1 = dis[s1], a2 = dis[s2], a3 = dis[s3];
        float b0 = dis[d0], b1 = dis[d1], b2 = dis[d2], b3 = dis[d3];
        int p0 = rowptr[d0], p1 = rowptr[d1], p2 = rowptr[d2], p3 = rowptr[d3];
        int o0 = atomicAdd(&cur[d0], 1);
        int o1 = atomicAdd(&cur[d1], 1);
        int o2 = atomicAdd(&cur[d2], 1);
        int o3 = atomicAdd(&cur[d3], 1);
        Edge e0{s0, a0 * b0}, e1{s1, a1 * b1}, e2{s2, a2 * b2}, e3{s3, a3 * b3};
        edges[p0 + o0] = e0;
        edges[p1 + o1] = e1;
        edges[p2 + o2] = e2;
        edges[p3 + o3] = e3;
    } else {
        for (int i = i0; i < E; ++i) {
            int s = src[i], d = dst[i];
            int slot = rowptr[d] + atomicAdd(&cur[d], 1);
            Edge e{s, dis[s] * dis[d]};
            edges[slot] = e;
        }
    }
}

// ---------------- tiled GEMM: out[N,96] = act(in)[N,K] @ W[K,96] (+bias) ----
// act = relu(x*ss[k] + ss[96+k]) when ACT. Block: 64 rows x 96 cols, thread 4x6.
// W staged per KC-panel (LDS ~21 KB -> high occupancy). HOUT: fp16 shadow copy.

template <int K, bool ACT, bool BIAS, bool HOUT>
__global__ __launch_bounds__(256) void gemm96(const float* __restrict__ in,
                                              const float* __restrict__ W,
                                              const float* __restrict__ bias,
                                              const float* __restrict__ ss,
                                              float* __restrict__ out,
                                              __half* __restrict__ hout, int N) {
    constexpr int KC = 32, PITCH = 68;
    __shared__ float Wl[KC * 96];      // 12 KB panel
    __shared__ float As[KC * PITCH];   // 8.5 KB
    const int tid = threadIdx.x;
    const int n0 = blockIdx.x * 64;
    const int tx = tid & 15, ty = tid >> 4;
    float acc[4][6];
#pragma unroll
    for (int r = 0; r < 4; ++r)
#pragma unroll
        for (int j = 0; j < 6; ++j) acc[r][j] = 0.0f;

    for (int k0 = 0; k0 < K; k0 += KC) {
        __syncthreads();
        // stage W panel: KC*96/4 = 768 float4, 3 per thread
#pragma unroll
        for (int f = tid; f < KC * 96 / 4; f += 256)
            ((float4*)Wl)[f] = ((const float4*)(W + (long long)k0 * 96))[f];
        // stage A panel (transposed)
#pragma unroll
        for (int t = tid; t < 512; t += 256) {
            int r = t >> 3, c = t & 7;
            int row = n0 + r;
            row = row < N ? row : N - 1;
            float4 v = *(const float4*)&in[(long long)row * K + k0 + 4 * c];
            if (ACT) {
                int kk = k0 + 4 * c;
                v.x = fmaxf(fmaf(v.x, ss[kk + 0], ss[96 + kk + 0]), 0.0f);
                v.y = fmaxf(fmaf(v.y, ss[kk + 1], ss[96 + kk + 1]), 0.0f);
                v.z = fmaxf(fmaf(v.z, ss[kk + 2], ss[96 + kk + 2]), 0.0f);
                v.w = fmaxf(fmaf(v.w, ss[kk + 3], ss[96 + kk + 3]), 0.0f);
            }
            As[(4 * c + 0) * PITCH + r] = v.x;
            As[(4 * c + 1) * PITCH + r] = v.y;
            As[(4 * c + 2) * PITCH + r] = v.z;
            As[(4 * c + 3) * PITCH + r] = v.w;
        }
        __syncthreads();
#pragma unroll
        for (int k = 0; k < KC; ++k) {
            float4 a4 = *(const float4*)&As[k * PITCH + 4 * ty];
            const float* wr = &Wl[k * 96 + 6 * tx];   // local panel k
            float w0 = wr[0], w1 = wr[1], w2 = wr[2], w3 = wr[3], w4 = wr[4], w5 = wr[5];
            float ar[4] = {a4.x, a4.y, a4.z, a4.w};
#pragma unroll
            for (int r = 0; r < 4; ++r) {
                acc[r][0] = fmaf(ar[r], w0, acc[r][0]);
                acc[r][1] = fmaf(ar[r], w1, acc[r][1]);
                acc[r][2] = fmaf(ar[r], w2, acc[r][2]);
                acc[r][3] = fmaf(ar[r], w3, acc[r][3]);
                acc[r][4] = fmaf(ar[r], w4, acc[r][4]);
                acc[r][5] = fmaf(ar[r], w5, acc[r][5]);
            }
        }
    }
    float bc[6];
#pragma unroll
    for (int j = 0; j < 6; ++j) bc[j] = BIAS ? bias[6 * tx + j] : 0.0f;
#pragma unroll
    for (int r = 0; r < 4; ++r) {
        int row = n0 + 4 * ty + r;
        if (row < N) {
            float o[6];
#pragma unroll
            for (int j = 0; j < 6; ++j) {
                o[j] = acc[r][j] + bc[j];
                out[(long long)row * 96 + 6 * tx + j] = o[j];
            }
            if (HOUT) {
#pragma unroll
                for (int j = 0; j < 6; j += 2) {
                    __half2 h2 = __floats2half2_rn(o[j], o[j + 1]);
                    *(__half2*)&hout[(long long)row * 96 + 6 * tx + j] = h2;
                }
            }
        }
    }
}

// ---------------- final GEMM: out[N,64] = l2norm(act(in) @ Wp2 + bp2) -------

__global__ __launch_bounds__(256) void gemm_final(const float* __restrict__ in,
                                                  const float* __restrict__ W,
                                                  const float* __restrict__ bias,
                                                  const float* __restrict__ ss,
                                                  float* __restrict__ out, int N) {
    constexpr int K = 96, KC = 32, PITCH = 68;
    __shared__ float Wl[KC * 64];      // 8 KB panel
    __shared__ float As[KC * PITCH];
    __shared__ float rs[64];
    const int tid = threadIdx.x;
    const int n0 = blockIdx.x * 64;
    const int tx = tid & 15, ty = tid >> 4;
    float acc[4][4];
#pragma unroll
    for (int r = 0; r < 4; ++r)
#pragma unroll
        for (int j = 0; j < 4; ++j) acc[r][j] = bias[4 * tx + j];

    for (int k0 = 0; k0 < K; k0 += KC) {
        __syncthreads();
#pragma unroll
        for (int f = tid; f < KC * 64 / 4; f += 256)
            ((float4*)Wl)[f] = ((const float4*)(W + (long long)k0 * 64))[f];
#pragma unroll
        for (int t = tid; t < 512; t += 256) {
            int r = t >> 3, c = t & 7;
            int row = n0 + r;
            row = row < N ? row : N - 1;
            float4 v = *(const float4*)&in[(long long)row * K + k0 + 4 * c];
            int kk = k0 + 4 * c;
            v.x = fmaxf(fmaf(v.x, ss[kk + 0], ss[96 + kk + 0]), 0.0f);
            v.y = fmaxf(fmaf(v.y, ss[kk + 1], ss[96 + kk + 1]), 0.0f);
            v.z = fmaxf(fmaf(v.z, ss[kk + 2], ss[96 + kk + 2]), 0.0f);
            v.w = fmaxf(fmaf(v.w, ss[kk + 3], ss[96 + kk + 3]), 0.0f);
            As[(4 * c + 0) * PITCH + r] = v.x;
            As[(4 * c + 1) * PITCH + r] = v.y;
            As[(4 * c + 2) * PITCH + r] = v.z;
            As[(4 * c + 3) * PITCH + r] = v.w;
        }
        __syncthreads();
#pragma unroll
        for (int k = 0; k < KC; ++k) {
            float4 a4 = *(const float4*)&As[k * PITCH + 4 * ty];
            float4 w4 = *(const float4*)&Wl[k * 64 + 4 * tx];
            float ar[4] = {a4.x, a4.y, a4.z, a4.w};
#pragma unroll
            for (int r = 0; r < 4; ++r) {
                acc[r][0] = fmaf(ar[r], w4.x, acc[r][0]);
                acc[r][1] = fmaf(ar[r], w4.y, acc[r][1]);
                acc[r][2] = fmaf(ar[r], w4.z, acc[r][2]);
                acc[r][3] = fmaf(ar[r], w4.w, acc[r][3]);
            }
        }
    }
    if (tid < 64) rs[tid] = 0.0f;
    __syncthreads();
#pragma unroll
    for (int r = 0; r < 4; ++r) {
        float p = acc[r][0] * acc[r][0] + acc[r][1] * acc[r][1] +
                  acc[r][2] * acc[r][2] + acc[r][3] * acc[r][3];
        atomicAdd(&rs[4 * ty + r], p);
    }
    __syncthreads();
#pragma unroll
    for (int r = 0; r < 4; ++r) {
        int row = n0 + 4 * ty + r;
        if (row < N) {
            float sc = 1.0f / fmaxf(sqrtf(rs[4 * ty + r]), 1e-12f);
            float4 o;
            o.x = acc[r][0] * sc; o.y = acc[r][1] * sc;
            o.z = acc[r][2] * sc; o.w = acc[r][3] * sc;
            *(float4*)&out[(long long)row * 64 + 4 * tx] = o;
        }
    }
}

// ---------------- CSR pull aggregation (fp16 gather path) ----------------
// out[n] = bias + dis[n]^2 * xw[n] + sum_e w_e * hxw[src_e]
// 12 threads per node, 8 cols (16 B fp16) each, edge loop unrolled x4.

__global__ __launch_bounds__(256) void agg96h(const float* __restrict__ xw,
                                              const __half* __restrict__ hxw,
                                              const int* __restrict__ rowptr,
                                              const Edge* __restrict__ edges,
                                              const float* __restrict__ dis,
                                              const float* __restrict__ bias,
                                              float* __restrict__ out, int N) {
    int idx = blockIdx.x * 256 + threadIdx.x;
    if (idx >= N * 12) return;
    int n = idx / 12, c8 = idx % 12;
    float d = dis[n];
    float dd = d * d;
    float acc[8];
    {
        const float4 x0 = *(const float4*)&xw[n * 96 + c8 * 8];
        const float4 x1 = *(const float4*)&xw[n * 96 + c8 * 8 + 4];
        acc[0] = fmaf(x0.x, dd, bias[c8 * 8 + 0]);
        acc[1] = fmaf(x0.y, dd, bias[c8 * 8 + 1]);
        acc[2] = fmaf(x0.z, dd, bias[c8 * 8 + 2]);
        acc[3] = fmaf(x0.w, dd, bias[c8 * 8 + 3]);
        acc[4] = fmaf(x1.x, dd, bias[c8 * 8 + 4]);
        acc[5] = fmaf(x1.y, dd, bias[c8 * 8 + 5]);
        acc[6] = fmaf(x1.z, dd, bias[c8 * 8 + 6]);
        acc[7] = fmaf(x1.w, dd, bias[c8 * 8 + 7]);
    }
    int e = rowptr[n], e1 = rowptr[n + 1];
    for (; e + 3 < e1; e += 4) {
        Edge E0 = edges[e], E1 = edges[e + 1], E2 = edges[e + 2], E3 = edges[e + 3];
        float4 g0 = *(const float4*)&hxw[E0.s * 96 + c8 * 8];
        float4 g1 = *(const float4*)&hxw[E1.s * 96 + c8 * 8];
        float4 g2 = *(const float4*)&hxw[E2.s * 96 + c8 * 8];
        float4 g3 = *(const float4*)&hxw[E3.s * 96 + c8 * 8];
        const __half2* h0 = (const __half2*)&g0;
        const __half2* h1 = (const __half2*)&g1;
        const __half2* h2 = (const __half2*)&g2;
        const __half2* h3 = (const __half2*)&g3;
#pragma unroll
        for (int k = 0; k < 4; ++k) {
            float2 f0 = __half22float2(h0[k]);
            float2 f1 = __half22float2(h1[k]);
            float2 f2 = __half22float2(h2[k]);
            float2 f3 = __half22float2(h3[k]);
            acc[2 * k + 0] = fmaf(f0.x, E0.w, acc[2 * k + 0]);
            acc[2 * k + 1] = fmaf(f0.y, E0.w, acc[2 * k + 1]);
            acc[2 * k + 0] = fmaf(f1.x, E1.w, acc[2 * k + 0]);
            acc[2 * k + 1] = fmaf(f1.y, E1.w, acc[2 * k + 1]);
            acc[2 * k + 0] = fmaf(f2.x, E2.w, acc[2 * k + 0]);
            acc[2 * k + 1] = fmaf(f2.y, E2.w, acc[2 * k + 1]);
            acc[2 * k + 0] = fmaf(f3.x, E3.w, acc[2 * k + 0]);
            acc[2 * k + 1] = fmaf(f3.y, E3.w, acc[2 * k + 1]);
        }
    }
    for (; e < e1; ++e) {
        Edge E0 = edges[e];
        float4 g0 = *(const float4*)&hxw[E0.s * 96 + c8 * 8];
        const __half2* h0 = (const __half2*)&g0;
#pragma unroll
        for (int k = 0; k < 4; ++k) {
            float2 f0 = __half22float2(h0[k]);
            acc[2 * k + 0] = fmaf(f0.x, E0.w, acc[2 * k + 0]);
            acc[2 * k + 1] = fmaf(f0.y, E0.w, acc[2 * k + 1]);
        }
    }
    float4 o0, o1;
    o0.x = acc[0]; o0.y = acc[1]; o0.z = acc[2]; o0.w = acc[3];
    o1.x = acc[4]; o1.y = acc[5]; o1.z = acc[6]; o1.w = acc[7];
    *(float4*)&out[n * 96 + c8 * 8] = o0;
    *(float4*)&out[n * 96 + c8 * 8 + 4] = o1;
}

// ---------------- BN stats (coalesced grid-stride) ----------------

__global__ __launch_bounds__(256) void bn_stats96(const float* __restrict__ h,
                                                  float* __restrict__ sums, int N) {
    __shared__ float sb[192];
    const int tid = threadIdx.x;
    if (tid < 192) sb[tid] = 0.0f;
    __syncthreads();
    int g = blockIdx.x * 256 + tid;
    int total = N * 24, stride = gridDim.x * 256;  // stride multiple of 24
    float4 s4 = {0, 0, 0, 0}, q4 = {0, 0, 0, 0};
    int c4 = g % 24;
    for (int i = g; i < total; i += stride) {
        int n = i / 24;
        float4 v = *(const float4*)&h[n * 96 + 4 * c4];
        s4.x += v.x; s4.y += v.y; s4.z += v.z; s4.w += v.w;
        q4.x += v.x * v.x; q4.y += v.y * v.y; q4.z += v.z * v.z; q4.w += v.w * v.w;
    }
    atomicAdd(&sb[4 * c4 + 0], s4.x);
    atomicAdd(&sb[4 * c4 + 1], s4.y);
    atomicAdd(&sb[4 * c4 + 2], s4.z);
    atomicAdd(&sb[4 * c4 + 3], s4.w);
    atomicAdd(&sb[96 + 4 * c4 + 0], q4.x);
    atomicAdd(&sb[96 + 4 * c4 + 1], q4.y);
    atomicAdd(&sb[96 + 4 * c4 + 2], q4.z);
    atomicAdd(&sb[96 + 4 * c4 + 3], q4.w);
    __syncthreads();
    if (tid < 192) atomicAdd(&sums[tid], sb[tid]);
}

__global__ void bn_finalize96(const float* __restrict__ sums, const float* __restrict__ gamma,
                              const float* __restrict__ beta, float* __restrict__ ss, int N) {
    int i = threadIdx.x;
    if (i < 96) {
        float inv_n = 1.0f / (float)N;
        float mean = sums[i] * inv_n;
        float var = sums[96 + i] * inv_n - mean * mean;
        float sc = gamma[i] * rsqrtf(var + 1e-5f);
        ss[i] = sc;
        ss[96 + i] = beta[i] - mean * sc;
    }
}

// ---------------- launch ----------------

extern "C" void kernel_launch(void* const* d_in, const int* in_sizes, int n_in,
                              void* d_out, int out_size, void* d_ws, size_t ws_size,
                              hipStream_t stream) {
    const float* x   = (const float*)d_in[0];
    const int*   ei  = (const int*)d_in[1];
    const float* W1  = (const float*)d_in[2];
    const float* b1  = (const float*)d_in[3];
    const float* g1  = (const float*)d_in[4];
    const float* be1 = (const float*)d_in[5];
    const float* W2  = (const float*)d_in[6];
    const float* b2  = (const float*)d_in[7];
    const float* g2  = (const float*)d_in[8];
    const float* be2 = (const float*)d_in[9];
    const float* Wp1 = (const float*)d_in[10];
    const float* bp1 = (const float*)d_in[11];
    const float* gp  = (const float*)d_in[12];
    const float* bep = (const float*)d_in[13];
    const float* Wp2 = (const float*)d_in[14];
    const float* bp2 = (const float*)d_in[15];

    const int N = in_sizes[0] / 128;   // 50000
    const int E = in_sizes[1] / 2;     // 800000
    const int* src = ei;
    const int* dst = ei + E;

    // workspace layout (~55 MB)
    char* w = (char*)d_ws;
    auto alloc = [&](size_t bytes) { char* p = w; w += (bytes + 15) & ~size_t(15); return p; };
    int*    cnt    = (int*)alloc((size_t)N * 4);
    int*    rowptr = (int*)alloc((size_t)(N + 1) * 4);
    int*    bsum   = (int*)alloc(64 * 4);
    int*    boff   = (int*)alloc(64 * 4);
    float*  dis    = (float*)alloc((size_t)N * 4);
    Edge*   edges  = (Edge*)alloc((size_t)E * 8);
    float*  buf1   = (float*)alloc((size_t)N * 96 * 4);
    float*  buf2   = (float*)alloc((size_t)N * 96 * 4);
    __half* hbuf   = (__half*)alloc((size_t)N * 96 * 2);
    float*  sums   = (float*)alloc(576 * 4);
    float*  ss     = (float*)alloc(576 * 4);
    float* sums1 = sums, *sums2 = sums + 192, *sums3 = sums + 384;
    float* ss1 = ss, *ss2 = ss + 192, *ss3 = ss + 384;

    float* out = (float*)d_out;

    const int gE4 = cdiv(E, BLK * 4);              // 4 edges/thread
    const int gG  = cdiv(N, 64);                   // 782 gemm blocks
    const int gA  = cdiv((long long)N * 12, BLK);  // 2344 agg blocks
    const int nb  = cdiv(N, 1024);                 // scan blocks (49)

    // CSR build
    zero_int<<<cdiv(N, BLK), BLK, 0, stream>>>(cnt, N);
    count_dst<<<gE4, BLK, 0, stream>>>(dst, cnt, E);
    dis_k<<<cdiv(N, BLK), BLK, 0, stream>>>(cnt, dis, N);
    scan1<<<nb, 256, 0, stream>>>(cnt, rowptr, bsum, N);
    scan2<<<1, 64, 0, stream>>>(bsum, boff, nb);
    scan3<<<cdiv(N, BLK), BLK, 0, stream>>>(rowptr, boff, N, E);
    zero_int<<<cdiv(N, BLK), BLK, 0, stream>>>(cnt, N);
    csr_fill<<<gE4, BLK, 0, stream>>>(src, dst, rowptr, cnt, dis, edges, E);
    zero_f<<<1, 576, 0, stream>>>(sums, 576);

    // layer 1
    gemm96<128, false, false, true><<<gG, 256, 0, stream>>>(x, W1, nullptr, nullptr, buf1, hbuf, N);
    agg96h<<<gA, 256, 0, stream>>>(buf1, hbuf, rowptr, edges, dis, b1, buf2, N);
    bn_stats96<<<960, 256, 0, stream>>>(buf2, sums1, N);
    bn_finalize96<<<1, 128, 0, stream>>>(sums1, g1, be1, ss1, N);

    // layer 2 (BN+ReLU of layer 1 fused into A staging)
    gemm96<96, true, false, true><<<gG, 256, 0, stream>>>(buf2, W2, nullptr, ss1, buf1, hbuf, N);
    agg96h<<<gA, 256, 0, stream>>>(buf1, hbuf, rowptr, edges, dis, b2, buf2, N);
    bn_stats96<<<960, 256, 0, stream>>>(buf2, sums2, N);
    bn_finalize96<<<1, 128, 0, stream>>>(sums2, g2, be2, ss2, N);

    // projector linear 1 (BN+ReLU of layer 2 fused)
    gemm96<96, true, true, false><<<gG, 256, 0, stream>>>(buf2, Wp1, bp1, ss2, buf1, nullptr, N);
    bn_stats96<<<960, 256, 0, stream>>>(buf1, sums3, N);
    bn_finalize96<<<1, 128, 0, stream>>>(sums3, gp, bep, ss3, N);

    // projector linear 2 + fused L2 normalize (BN+ReLU fused)
    gemm_final<<<gG, 256, 0, stream>>>(buf1, Wp2, bp2, ss3, out, N);
}

// Round 7
// 444.510 us; speedup vs baseline: 3.0901x; 1.1040x over previous
//
#include <hip/hip_runtime.h>
#include <hip/hip_fp16.h>

constexpr int BLK = 256;

static inline int cdiv(long long a, int b) { return (int)((a + b - 1) / b); }

struct Edge { int s; float w; };  // 8 B

// ---------------- utility ----------------

__global__ void zero_int(int* __restrict__ p, int n) {
    for (int i = blockIdx.x * blockDim.x + threadIdx.x; i < n; i += gridDim.x * blockDim.x)
        p[i] = 0;
}

__global__ void zero_f(float* __restrict__ p, int n) {
    for (int i = blockIdx.x * blockDim.x + threadIdx.x; i < n; i += gridDim.x * blockDim.x)
        p[i] = 0.0f;
}

// ---------------- degree / CSR build ----------------

// count in-degree AND record each edge's within-node offset (coalesced write)
__global__ void count_dst_off(const int* __restrict__ dst, int* __restrict__ cnt,
                              int* __restrict__ eoff, int E) {
    for (int i = blockIdx.x * blockDim.x + threadIdx.x; i < E; i += gridDim.x * blockDim.x)
        eoff[i] = atomicAdd(&cnt[dst[i]], 1);
}

__global__ void dis_k(const int* __restrict__ cnt, float* __restrict__ dis, int N) {
    for (int i = blockIdx.x * blockDim.x + threadIdx.x; i < N; i += gridDim.x * blockDim.x)
        dis[i] = rsqrtf((float)cnt[i] + 1.0f);  // +1 self-loop
}

// block scans 1024 elements (256 threads x 4)
__global__ void scan1(const int* __restrict__ cnt, int* __restrict__ rowptr,
                      int* __restrict__ bsum, int N) {
    __shared__ int ts[256];
    int tid = threadIdx.x;
    int base = blockIdx.x * 1024 + tid * 4;
    int v[4], s = 0;
#pragma unroll
    for (int i = 0; i < 4; ++i) {
        v[i] = (base + i < N) ? cnt[base + i] : 0;
        s += v[i];
    }
    ts[tid] = s;
    __syncthreads();
    for (int off = 1; off < 256; off <<= 1) {
        int t = 0;
        if (tid >= off) t = ts[tid - off];
        __syncthreads();
        if (tid >= off) ts[tid] += t;
        __syncthreads();
    }
    int run = ts[tid] - s;
#pragma unroll
    for (int i = 0; i < 4; ++i) {
        if (base + i < N) rowptr[base + i] = run;
        run += v[i];
    }
    if (tid == 255) bsum[blockIdx.x] = ts[255];
}

// wave shuffle-scan over block sums (nb <= 64)
__global__ void scan2(const int* __restrict__ bsum, int* __restrict__ boff, int nb) {
    int lane = threadIdx.x;  // 64 threads
    int orig = (lane < nb) ? bsum[lane] : 0;
    int v = orig;
#pragma unroll
    for (int off = 1; off < 64; off <<= 1) {
        int t = __shfl_up(v, off, 64);
        if (lane >= off) v += t;
    }
    if (lane < nb) boff[lane] = v - orig;  // exclusive
}

__global__ void scan3(int* __restrict__ rowptr, const int* __restrict__ boff, int N, int E) {
    int i = blockIdx.x * blockDim.x + threadIdx.x;
    if (i < N) rowptr[i] += boff[i >> 10];
    if (i == 0) rowptr[N] = E;
}

// atomic-free scatter: slot = rowptr[dst] + eoff (bijection)
__global__ void csr_fill(const int* __restrict__ src, const int* __restrict__ dst,
                         const int* __restrict__ eoff, const int* __restrict__ rowptr,
                         const float* __restrict__ dis, Edge* __restrict__ edges, int E) {
    for (int i = blockIdx.x * blockDim.x + threadIdx.x; i < E; i += gridDim.x * blockDim.x) {
        int s = src[i], d = dst[i];
        Edge e{s, dis[s] * dis[d]};
        edges[rowptr[d] + eoff[i]] = e;
    }
}

// ---------------- tiled GEMM: out[N,96] = act(in)[N,K] @ W[K,96] (+bias) ----
// act = relu(x*ss[k] + ss[96+k]) when ACT. Block: 64 rows x 96 cols, thread 4x6.
// W staged per KC-panel (LDS ~21 KB -> high occupancy). HOUT: fp16 shadow copy.

template <int K, bool ACT, bool BIAS, bool HOUT>
__global__ __launch_bounds__(256) void gemm96(const float* __restrict__ in,
                                              const float* __restrict__ W,
                                              const float* __restrict__ bias,
                                              const float* __restrict__ ss,
                                              float* __restrict__ out,
                                              __half* __restrict__ hout, int N) {
    constexpr int KC = 32, PITCH = 68;
    __shared__ float Wl[KC * 96];      // 12 KB panel
    __shared__ float As[KC * PITCH];   // 8.5 KB
    const int tid = threadIdx.x;
    const int n0 = blockIdx.x * 64;
    const int tx = tid & 15, ty = tid >> 4;
    float acc[4][6];
#pragma unroll
    for (int r = 0; r < 4; ++r)
#pragma unroll
        for (int j = 0; j < 6; ++j) acc[r][j] = 0.0f;

    for (int k0 = 0; k0 < K; k0 += KC) {
        __syncthreads();
#pragma unroll
        for (int f = tid; f < KC * 96 / 4; f += 256)
            ((float4*)Wl)[f] = ((const float4*)(W + (long long)k0 * 96))[f];
#pragma unroll
        for (int t = tid; t < 512; t += 256) {
            int r = t >> 3, c = t & 7;
            int row = n0 + r;
            row = row < N ? row : N - 1;
            float4 v = *(const float4*)&in[(long long)row * K + k0 + 4 * c];
            if (ACT) {
                int kk = k0 + 4 * c;
                v.x = fmaxf(fmaf(v.x, ss[kk + 0], ss[96 + kk + 0]), 0.0f);
                v.y = fmaxf(fmaf(v.y, ss[kk + 1], ss[96 + kk + 1]), 0.0f);
                v.z = fmaxf(fmaf(v.z, ss[kk + 2], ss[96 + kk + 2]), 0.0f);
                v.w = fmaxf(fmaf(v.w, ss[kk + 3], ss[96 + kk + 3]), 0.0f);
            }
            As[(4 * c + 0) * PITCH + r] = v.x;
            As[(4 * c + 1) * PITCH + r] = v.y;
            As[(4 * c + 2) * PITCH + r] = v.z;
            As[(4 * c + 3) * PITCH + r] = v.w;
        }
        __syncthreads();
#pragma unroll
        for (int k = 0; k < KC; ++k) {
            float4 a4 = *(const float4*)&As[k * PITCH + 4 * ty];
            const float* wr = &Wl[k * 96 + 6 * tx];
            float w0 = wr[0], w1 = wr[1], w2 = wr[2], w3 = wr[3], w4 = wr[4], w5 = wr[5];
            float ar[4] = {a4.x, a4.y, a4.z, a4.w};
#pragma unroll
            for (int r = 0; r < 4; ++r) {
                acc[r][0] = fmaf(ar[r], w0, acc[r][0]);
                acc[r][1] = fmaf(ar[r], w1, acc[r][1]);
                acc[r][2] = fmaf(ar[r], w2, acc[r][2]);
                acc[r][3] = fmaf(ar[r], w3, acc[r][3]);
                acc[r][4] = fmaf(ar[r], w4, acc[r][4]);
                acc[r][5] = fmaf(ar[r], w5, acc[r][5]);
            }
        }
    }
    float bc[6];
#pragma unroll
    for (int j = 0; j < 6; ++j) bc[j] = BIAS ? bias[6 * tx + j] : 0.0f;
#pragma unroll
    for (int r = 0; r < 4; ++r) {
        int row = n0 + 4 * ty + r;
        if (row < N) {
            float o[6];
#pragma unroll
            for (int j = 0; j < 6; ++j) {
                o[j] = acc[r][j] + bc[j];
                out[(long long)row * 96 + 6 * tx + j] = o[j];
            }
            if (HOUT) {
#pragma unroll
                for (int j = 0; j < 6; j += 2) {
                    __half2 h2 = __floats2half2_rn(o[j], o[j + 1]);
                    *(__half2*)&hout[(long long)row * 96 + 6 * tx + j] = h2;
                }
            }
        }
    }
}

// ---------------- final GEMM: out[N,64] = l2norm(act(in) @ Wp2 + bp2) -------

__global__ __launch_bounds__(256) void gemm_final(const float* __restrict__ in,
                                                  const float* __restrict__ W,
                                                  const float* __restrict__ bias,
                                                  const float* __restrict__ ss,
                                                  float* __restrict__ out, int N) {
    constexpr int K = 96, KC = 32, PITCH = 68;
    __shared__ float Wl[KC * 64];
    __shared__ float As[KC * PITCH];
    __shared__ float rs[64];
    const int tid = threadIdx.x;
    const int n0 = blockIdx.x * 64;
    const int tx = tid & 15, ty = tid >> 4;
    float acc[4][4];
#pragma unroll
    for (int r = 0; r < 4; ++r)
#pragma unroll
        for (int j = 0; j < 4; ++j) acc[r][j] = bias[4 * tx + j];

    for (int k0 = 0; k0 < K; k0 += KC) {
        __syncthreads();
#pragma unroll
        for (int f = tid; f < KC * 64 / 4; f += 256)
            ((float4*)Wl)[f] = ((const float4*)(W + (long long)k0 * 64))[f];
#pragma unroll
        for (int t = tid; t < 512; t += 256) {
            int r = t >> 3, c = t & 7;
            int row = n0 + r;
            row = row < N ? row : N - 1;
            float4 v = *(const float4*)&in[(long long)row * K + k0 + 4 * c];
            int kk = k0 + 4 * c;
            v.x = fmaxf(fmaf(v.x, ss[kk + 0], ss[96 + kk + 0]), 0.0f);
            v.y = fmaxf(fmaf(v.y, ss[kk + 1], ss[96 + kk + 1]), 0.0f);
            v.z = fmaxf(fmaf(v.z, ss[kk + 2], ss[96 + kk + 2]), 0.0f);
            v.w = fmaxf(fmaf(v.w, ss[kk + 3], ss[96 + kk + 3]), 0.0f);
            As[(4 * c + 0) * PITCH + r] = v.x;
            As[(4 * c + 1) * PITCH + r] = v.y;
            As[(4 * c + 2) * PITCH + r] = v.z;
            As[(4 * c + 3) * PITCH + r] = v.w;
        }
        __syncthreads();
#pragma unroll
        for (int k = 0; k < KC; ++k) {
            float4 a4 = *(const float4*)&As[k * PITCH + 4 * ty];
            float4 w4 = *(const float4*)&Wl[k * 64 + 4 * tx];
            float ar[4] = {a4.x, a4.y, a4.z, a4.w};
#pragma unroll
            for (int r = 0; r < 4; ++r) {
                acc[r][0] = fmaf(ar[r], w4.x, acc[r][0]);
                acc[r][1] = fmaf(ar[r], w4.y, acc[r][1]);
                acc[r][2] = fmaf(ar[r], w4.z, acc[r][2]);
                acc[r][3] = fmaf(ar[r], w4.w, acc[r][3]);
            }
        }
    }
    if (tid < 64) rs[tid] = 0.0f;
    __syncthreads();
#pragma unroll
    for (int r = 0; r < 4; ++r) {
        float p = acc[r][0] * acc[r][0] + acc[r][1] * acc[r][1] +
                  acc[r][2] * acc[r][2] + acc[r][3] * acc[r][3];
        atomicAdd(&rs[4 * ty + r], p);
    }
    __syncthreads();
#pragma unroll
    for (int r = 0; r < 4; ++r) {
        int row = n0 + 4 * ty + r;
        if (row < N) {
            float sc = 1.0f / fmaxf(sqrtf(rs[4 * ty + r]), 1e-12f);
            float4 o;
            o.x = acc[r][0] * sc; o.y = acc[r][1] * sc;
            o.z = acc[r][2] * sc; o.w = acc[r][3] * sc;
            *(float4*)&out[(long long)row * 64 + 4 * tx] = o;
        }
    }
}

// ---------------- CSR pull aggregation (fp16 gather path) ----------------
// out[n] = bias + dis[n]^2 * xw[n] + sum_e w_e * hxw[src_e]
// 12 threads per node, 8 cols (16 B fp16) each, edge loop unrolled x4.

__global__ __launch_bounds__(256) void agg96h(const float* __restrict__ xw,
                                              const __half* __restrict__ hxw,
                                              const int* __restrict__ rowptr,
                                              const Edge* __restrict__ edges,
                                              const float* __restrict__ dis,
                                              const float* __restrict__ bias,
                                              float* __restrict__ out, int N) {
    int idx = blockIdx.x * 256 + threadIdx.x;
    if (idx >= N * 12) return;
    int n = idx / 12, c8 = idx % 12;
    float d = dis[n];
    float dd = d * d;
    float acc[8];
    {
        const float4 x0 = *(const float4*)&xw[n * 96 + c8 * 8];
        const float4 x1 = *(const float4*)&xw[n * 96 + c8 * 8 + 4];
        acc[0] = fmaf(x0.x, dd, bias[c8 * 8 + 0]);
        acc[1] = fmaf(x0.y, dd, bias[c8 * 8 + 1]);
        acc[2] = fmaf(x0.z, dd, bias[c8 * 8 + 2]);
        acc[3] = fmaf(x0.w, dd, bias[c8 * 8 + 3]);
        acc[4] = fmaf(x1.x, dd, bias[c8 * 8 + 4]);
        acc[5] = fmaf(x1.y, dd, bias[c8 * 8 + 5]);
        acc[6] = fmaf(x1.z, dd, bias[c8 * 8 + 6]);
        acc[7] = fmaf(x1.w, dd, bias[c8 * 8 + 7]);
    }
    int e = rowptr[n], e1 = rowptr[n + 1];
    for (; e + 3 < e1; e += 4) {
        Edge E0 = edges[e], E1 = edges[e + 1], E2 = edges[e + 2], E3 = edges[e + 3];
        float4 g0 = *(const float4*)&hxw[E0.s * 96 + c8 * 8];
        float4 g1 = *(const float4*)&hxw[E1.s * 96 + c8 * 8];
        float4 g2 = *(const float4*)&hxw[E2.s * 96 + c8 * 8];
        float4 g3 = *(const float4*)&hxw[E3.s * 96 + c8 * 8];
        const __half2* h0 = (const __half2*)&g0;
        const __half2* h1 = (const __half2*)&g1;
        const __half2* h2 = (const __half2*)&g2;
        const __half2* h3 = (const __half2*)&g3;
#pragma unroll
        for (int k = 0; k < 4; ++k) {
            float2 f0 = __half22float2(h0[k]);
            float2 f1 = __half22float2(h1[k]);
            float2 f2 = __half22float2(h2[k]);
            float2 f3 = __half22float2(h3[k]);
            acc[2 * k + 0] = fmaf(f0.x, E0.w, acc[2 * k + 0]);
            acc[2 * k + 1] = fmaf(f0.y, E0.w, acc[2 * k + 1]);
            acc[2 * k + 0] = fmaf(f1.x, E1.w, acc[2 * k + 0]);
            acc[2 * k + 1] = fmaf(f1.y, E1.w, acc[2 * k + 1]);
            acc[2 * k + 0] = fmaf(f2.x, E2.w, acc[2 * k + 0]);
            acc[2 * k + 1] = fmaf(f2.y, E2.w, acc[2 * k + 1]);
            acc[2 * k + 0] = fmaf(f3.x, E3.w, acc[2 * k + 0]);
            acc[2 * k + 1] = fmaf(f3.y, E3.w, acc[2 * k + 1]);
        }
    }
    for (; e < e1; ++e) {
        Edge E0 = edges[e];
        float4 g0 = *(const float4*)&hxw[E0.s * 96 + c8 * 8];
        const __half2* h0 = (const __half2*)&g0;
#pragma unroll
        for (int k = 0; k < 4; ++k) {
            float2 f0 = __half22float2(h0[k]);
            acc[2 * k + 0] = fmaf(f0.x, E0.w, acc[2 * k + 0]);
            acc[2 * k + 1] = fmaf(f0.y, E0.w, acc[2 * k + 1]);
        }
    }
    float4 o0, o1;
    o0.x = acc[0]; o0.y = acc[1]; o0.z = acc[2]; o0.w = acc[3];
    o1.x = acc[4]; o1.y = acc[5]; o1.z = acc[6]; o1.w = acc[7];
    *(float4*)&out[n * 96 + c8 * 8] = o0;
    *(float4*)&out[n * 96 + c8 * 8 + 4] = o1;
}

// ---------------- BN stats (coalesced grid-stride) ----------------

__global__ __launch_bounds__(256) void bn_stats96(const float* __restrict__ h,
                                                  float* __restrict__ sums, int N) {
    __shared__ float sb[192];
    const int tid = threadIdx.x;
    if (tid < 192) sb[tid] = 0.0f;
    __syncthreads();
    int g = blockIdx.x * 256 + tid;
    int total = N * 24, stride = gridDim.x * 256;  // stride multiple of 24
    float4 s4 = {0, 0, 0, 0}, q4 = {0, 0, 0, 0};
    int c4 = g % 24;
    for (int i = g; i < total; i += stride) {
        int n = i / 24;
        float4 v = *(const float4*)&h[n * 96 + 4 * c4];
        s4.x += v.x; s4.y += v.y; s4.z += v.z; s4.w += v.w;
        q4.x += v.x * v.x; q4.y += v.y * v.y; q4.z += v.z * v.z; q4.w += v.w * v.w;
    }
    atomicAdd(&sb[4 * c4 + 0], s4.x);
    atomicAdd(&sb[4 * c4 + 1], s4.y);
    atomicAdd(&sb[4 * c4 + 2], s4.z);
    atomicAdd(&sb[4 * c4 + 3], s4.w);
    atomicAdd(&sb[96 + 4 * c4 + 0], q4.x);
    atomicAdd(&sb[96 + 4 * c4 + 1], q4.y);
    atomicAdd(&sb[96 + 4 * c4 + 2], q4.z);
    atomicAdd(&sb[96 + 4 * c4 + 3], q4.w);
    __syncthreads();
    if (tid < 192) atomicAdd(&sums[tid], sb[tid]);
}

__global__ void bn_finalize96(const float* __restrict__ sums, const float* __restrict__ gamma,
                              const float* __restrict__ beta, float* __restrict__ ss, int N) {
    int i = threadIdx.x;
    if (i < 96) {
        float inv_n = 1.0f / (float)N;
        float mean = sums[i] * inv_n;
        float var = sums[96 + i] * inv_n - mean * mean;
        float sc = gamma[i] * rsqrtf(var + 1e-5f);
        ss[i] = sc;
        ss[96 + i] = beta[i] - mean * sc;
    }
}

// ---------------- launch ----------------

extern "C" void kernel_launch(void* const* d_in, const int* in_sizes, int n_in,
                              void* d_out, int out_size, void* d_ws, size_t ws_size,
                              hipStream_t stream) {
    const float* x   = (const float*)d_in[0];
    const int*   ei  = (const int*)d_in[1];
    const float* W1  = (const float*)d_in[2];
    const float* b1  = (const float*)d_in[3];
    const float* g1  = (const float*)d_in[4];
    const float* be1 = (const float*)d_in[5];
    const float* W2  = (const float*)d_in[6];
    const float* b2  = (const float*)d_in[7];
    const float* g2  = (const float*)d_in[8];
    const float* be2 = (const float*)d_in[9];
    const float* Wp1 = (const float*)d_in[10];
    const float* bp1 = (const float*)d_in[11];
    const float* gp  = (const float*)d_in[12];
    const float* bep = (const float*)d_in[13];
    const float* Wp2 = (const float*)d_in[14];
    const float* bp2 = (const float*)d_in[15];

    const int N = in_sizes[0] / 128;   // 50000
    const int E = in_sizes[1] / 2;     // 800000
    const int* src = ei;
    const int* dst = ei + E;

    // workspace layout (~58 MB)
    char* w = (char*)d_ws;
    auto alloc = [&](size_t bytes) { char* p = w; w += (bytes + 15) & ~size_t(15); return p; };
    int*    cnt    = (int*)alloc((size_t)N * 4);
    int*    rowptr = (int*)alloc((size_t)(N + 1) * 4);
    int*    bsum   = (int*)alloc(64 * 4);
    int*    boff   = (int*)alloc(64 * 4);
    float*  dis    = (float*)alloc((size_t)N * 4);
    int*    eoff   = (int*)alloc((size_t)E * 4);
    Edge*   edges  = (Edge*)alloc((size_t)E * 8);
    float*  buf1   = (float*)alloc((size_t)N * 96 * 4);
    float*  buf2   = (float*)alloc((size_t)N * 96 * 4);
    __half* hbuf   = (__half*)alloc((size_t)N * 96 * 2);
    float*  sums   = (float*)alloc(576 * 4);
    float*  ss     = (float*)alloc(576 * 4);
    float* sums1 = sums, *sums2 = sums + 192, *sums3 = sums + 384;
    float* ss1 = ss, *ss2 = ss + 192, *ss3 = ss + 384;

    float* out = (float*)d_out;

    const int gE  = cdiv(E, BLK);                  // 3125 blocks, 1 edge/thread
    const int gG  = cdiv(N, 64);                   // 782 gemm blocks
    const int gA  = cdiv((long long)N * 12, BLK);  // 2344 agg blocks
    const int nb  = cdiv(N, 1024);                 // scan blocks (49)

    // CSR build (atomic-free scatter: slot = rowptr[dst] + eoff)
    zero_int<<<cdiv(N, BLK), BLK, 0, stream>>>(cnt, N);
    count_dst_off<<<gE, BLK, 0, stream>>>(dst, cnt, eoff, E);
    dis_k<<<cdiv(N, BLK), BLK, 0, stream>>>(cnt, dis, N);
    scan1<<<nb, 256, 0, stream>>>(cnt, rowptr, bsum, N);
    scan2<<<1, 64, 0, stream>>>(bsum, boff, nb);
    scan3<<<cdiv(N, BLK), BLK, 0, stream>>>(rowptr, boff, N, E);
    csr_fill<<<gE, BLK, 0, stream>>>(src, dst, eoff, rowptr, dis, edges, E);
    zero_f<<<1, 576, 0, stream>>>(sums, 576);

    // layer 1
    gemm96<128, false, false, true><<<gG, 256, 0, stream>>>(x, W1, nullptr, nullptr, buf1, hbuf, N);
    agg96h<<<gA, 256, 0, stream>>>(buf1, hbuf, rowptr, edges, dis, b1, buf2, N);
    bn_stats96<<<960, 256, 0, stream>>>(buf2, sums1, N);
    bn_finalize96<<<1, 128, 0, stream>>>(sums1, g1, be1, ss1, N);

    // layer 2 (BN+ReLU of layer 1 fused into A staging)
    gemm96<96, true, false, true><<<gG, 256, 0, stream>>>(buf2, W2, nullptr, ss1, buf1, hbuf, N);
    agg96h<<<gA, 256, 0, stream>>>(buf1, hbuf, rowptr, edges, dis, b2, buf2, N);
    bn_stats96<<<960, 256, 0, stream>>>(buf2, sums2, N);
    bn_finalize96<<<1, 128, 0, stream>>>(sums2, g2, be2, ss2, N);

    // projector linear 1 (BN+ReLU of layer 2 fused)
    gemm96<96, true, true, false><<<gG, 256, 0, stream>>>(buf2, Wp1, bp1, ss2, buf1, nullptr, N);
    bn_stats96<<<960, 256, 0, stream>>>(buf1, sums3, N);
    bn_finalize96<<<1, 128, 0, stream>>>(sums3, gp, bep, ss3, N);

    // projector linear 2 + fused L2 normalize (BN+ReLU fused)
    gemm_final<<<gG, 256, 0, stream>>>(buf1, Wp2, bp2, ss3, out, N);
}

// Round 8
// 391.441 us; speedup vs baseline: 3.5090x; 1.1356x over previous
//
#include <hip/hip_runtime.h>
#include <hip/hip_fp16.h>

constexpr int BLK = 256;

static inline int cdiv(long long a, int b) { return (int)((a + b - 1) / b); }

// ---------------- utility ----------------

__global__ void zero_int(int* __restrict__ p, int n) {
    for (int i = blockIdx.x * blockDim.x + threadIdx.x; i < n; i += gridDim.x * blockDim.x)
        p[i] = 0;
}

// ---------------- degree / CSR build ----------------

// count in-degree AND record each edge's within-node offset (coalesced write)
__global__ void count_dst_off(const int* __restrict__ dst, int* __restrict__ cnt,
                              int* __restrict__ eoff, int E) {
    for (int i = blockIdx.x * blockDim.x + threadIdx.x; i < E; i += gridDim.x * blockDim.x)
        eoff[i] = atomicAdd(&cnt[dst[i]], 1);
}

// block scans 1024 elements (256 threads x 4); also emits dis = rsqrt(cnt+1)
__global__ void scan1_dis(const int* __restrict__ cnt, int* __restrict__ rowptr,
                          int* __restrict__ bsum, float* __restrict__ dis, int N) {
    __shared__ int ts[256];
    int tid = threadIdx.x;
    int base = blockIdx.x * 1024 + tid * 4;
    int v[4], s = 0;
#pragma unroll
    for (int i = 0; i < 4; ++i) {
        v[i] = (base + i < N) ? cnt[base + i] : 0;
        s += v[i];
        if (base + i < N) dis[base + i] = rsqrtf((float)v[i] + 1.0f);
    }
    ts[tid] = s;
    __syncthreads();
    for (int off = 1; off < 256; off <<= 1) {
        int t = 0;
        if (tid >= off) t = ts[tid - off];
        __syncthreads();
        if (tid >= off) ts[tid] += t;
        __syncthreads();
    }
    int run = ts[tid] - s;
#pragma unroll
    for (int i = 0; i < 4; ++i) {
        if (base + i < N) rowptr[base + i] = run;
        run += v[i];
    }
    if (tid == 255) bsum[blockIdx.x] = ts[255];
}

// wave shuffle-scan over block sums (nb <= 64) + zero the BN sums buffer
__global__ void scan2z(const int* __restrict__ bsum, int* __restrict__ boff, int nb,
                       float* __restrict__ sums) {
    int tid = threadIdx.x;  // 640 threads
    if (tid < 64) {
        int orig = (tid < nb) ? bsum[tid] : 0;
        int v = orig;
#pragma unroll
        for (int off = 1; off < 64; off <<= 1) {
            int t = __shfl_up(v, off, 64);
            if (tid >= off) v += t;
        }
        if (tid < nb) boff[tid] = v - orig;  // exclusive
    } else if (tid < 64 + 576) {
        sums[tid - 64] = 0.0f;
    }
}

__global__ void scan3(int* __restrict__ rowptr, const int* __restrict__ boff, int N, int E) {
    int i = blockIdx.x * blockDim.x + threadIdx.x;
    if (i < N) rowptr[i] += boff[i >> 10];
    if (i == 0) rowptr[N] = E;
}

// atomic-free scatter of 4-B src index: slot = rowptr[dst] + eoff (bijection)
__global__ void csr_fill(const int* __restrict__ src, const int* __restrict__ dst,
                         const int* __restrict__ eoff, const int* __restrict__ rowptr,
                         int* __restrict__ csrc, int E) {
    for (int i = blockIdx.x * blockDim.x + threadIdx.x; i < E; i += gridDim.x * blockDim.x) {
        csrc[rowptr[dst[i]] + eoff[i]] = src[i];
    }
}

// ---------------- tiled GEMM: act(in)[N,K] @ W[K,96] (+bias) ----------------
// act = relu(x*ss[k] + ss[96+k]) when ACT. Block: 64 rows x 96 cols, thread 4x6.
// WOUT: fp32 output; HOUT: fp16 shadow output (gather path).

template <int K, bool ACT, bool BIAS, bool HOUT, bool WOUT>
__global__ __launch_bounds__(256) void gemm96(const float* __restrict__ in,
                                              const float* __restrict__ W,
                                              const float* __restrict__ bias,
                                              const float* __restrict__ ss,
                                              float* __restrict__ out,
                                              __half* __restrict__ hout, int N) {
    constexpr int KC = 32, PITCH = 68;
    __shared__ float Wl[KC * 96];      // 12 KB panel
    __shared__ float As[KC * PITCH];   // 8.5 KB
    const int tid = threadIdx.x;
    const int n0 = blockIdx.x * 64;
    const int tx = tid & 15, ty = tid >> 4;
    float acc[4][6];
#pragma unroll
    for (int r = 0; r < 4; ++r)
#pragma unroll
        for (int j = 0; j < 6; ++j) acc[r][j] = 0.0f;

    for (int k0 = 0; k0 < K; k0 += KC) {
        __syncthreads();
#pragma unroll
        for (int f = tid; f < KC * 96 / 4; f += 256)
            ((float4*)Wl)[f] = ((const float4*)(W + (long long)k0 * 96))[f];
#pragma unroll
        for (int t = tid; t < 512; t += 256) {
            int r = t >> 3, c = t & 7;
            int row = n0 + r;
            row = row < N ? row : N - 1;
            float4 v = *(const float4*)&in[(long long)row * K + k0 + 4 * c];
            if (ACT) {
                int kk = k0 + 4 * c;
                v.x = fmaxf(fmaf(v.x, ss[kk + 0], ss[96 + kk + 0]), 0.0f);
                v.y = fmaxf(fmaf(v.y, ss[kk + 1], ss[96 + kk + 1]), 0.0f);
                v.z = fmaxf(fmaf(v.z, ss[kk + 2], ss[96 + kk + 2]), 0.0f);
                v.w = fmaxf(fmaf(v.w, ss[kk + 3], ss[96 + kk + 3]), 0.0f);
            }
            As[(4 * c + 0) * PITCH + r] = v.x;
            As[(4 * c + 1) * PITCH + r] = v.y;
            As[(4 * c + 2) * PITCH + r] = v.z;
            As[(4 * c + 3) * PITCH + r] = v.w;
        }
        __syncthreads();
#pragma unroll
        for (int k = 0; k < KC; ++k) {
            float4 a4 = *(const float4*)&As[k * PITCH + 4 * ty];
            const float* wr = &Wl[k * 96 + 6 * tx];
            float w0 = wr[0], w1 = wr[1], w2 = wr[2], w3 = wr[3], w4 = wr[4], w5 = wr[5];
            float ar[4] = {a4.x, a4.y, a4.z, a4.w};
#pragma unroll
            for (int r = 0; r < 4; ++r) {
                acc[r][0] = fmaf(ar[r], w0, acc[r][0]);
                acc[r][1] = fmaf(ar[r], w1, acc[r][1]);
                acc[r][2] = fmaf(ar[r], w2, acc[r][2]);
                acc[r][3] = fmaf(ar[r], w3, acc[r][3]);
                acc[r][4] = fmaf(ar[r], w4, acc[r][4]);
                acc[r][5] = fmaf(ar[r], w5, acc[r][5]);
            }
        }
    }
    float bc[6];
#pragma unroll
    for (int j = 0; j < 6; ++j) bc[j] = BIAS ? bias[6 * tx + j] : 0.0f;
#pragma unroll
    for (int r = 0; r < 4; ++r) {
        int row = n0 + 4 * ty + r;
        if (row < N) {
            float o[6];
#pragma unroll
            for (int j = 0; j < 6; ++j) o[j] = acc[r][j] + bc[j];
            if (WOUT) {
#pragma unroll
                for (int j = 0; j < 6; ++j)
                    out[(long long)row * 96 + 6 * tx + j] = o[j];
            }
            if (HOUT) {
#pragma unroll
                for (int j = 0; j < 6; j += 2) {
                    __half2 h2 = __floats2half2_rn(o[j], o[j + 1]);
                    *(__half2*)&hout[(long long)row * 96 + 6 * tx + j] = h2;
                }
            }
        }
    }
}

// ---------------- final GEMM: out[N,64] = l2norm(act(in) @ Wp2 + bp2) -------

__global__ __launch_bounds__(256) void gemm_final(const float* __restrict__ in,
                                                  const float* __restrict__ W,
                                                  const float* __restrict__ bias,
                                                  const float* __restrict__ ss,
                                                  float* __restrict__ out, int N) {
    constexpr int K = 96, KC = 32, PITCH = 68;
    __shared__ float Wl[KC * 64];
    __shared__ float As[KC * PITCH];
    __shared__ float rs[64];
    const int tid = threadIdx.x;
    const int n0 = blockIdx.x * 64;
    const int tx = tid & 15, ty = tid >> 4;
    float acc[4][4];
#pragma unroll
    for (int r = 0; r < 4; ++r)
#pragma unroll
        for (int j = 0; j < 4; ++j) acc[r][j] = bias[4 * tx + j];

    for (int k0 = 0; k0 < K; k0 += KC) {
        __syncthreads();
#pragma unroll
        for (int f = tid; f < KC * 64 / 4; f += 256)
            ((float4*)Wl)[f] = ((const float4*)(W + (long long)k0 * 64))[f];
#pragma unroll
        for (int t = tid; t < 512; t += 256) {
            int r = t >> 3, c = t & 7;
            int row = n0 + r;
            row = row < N ? row : N - 1;
            float4 v = *(const float4*)&in[(long long)row * K + k0 + 4 * c];
            int kk = k0 + 4 * c;
            v.x = fmaxf(fmaf(v.x, ss[kk + 0], ss[96 + kk + 0]), 0.0f);
            v.y = fmaxf(fmaf(v.y, ss[kk + 1], ss[96 + kk + 1]), 0.0f);
            v.z = fmaxf(fmaf(v.z, ss[kk + 2], ss[96 + kk + 2]), 0.0f);
            v.w = fmaxf(fmaf(v.w, ss[kk + 3], ss[96 + kk + 3]), 0.0f);
            As[(4 * c + 0) * PITCH + r] = v.x;
            As[(4 * c + 1) * PITCH + r] = v.y;
            As[(4 * c + 2) * PITCH + r] = v.z;
            As[(4 * c + 3) * PITCH + r] = v.w;
        }
        __syncthreads();
#pragma unroll
        for (int k = 0; k < KC; ++k) {
            float4 a4 = *(const float4*)&As[k * PITCH + 4 * ty];
            float4 w4 = *(const float4*)&Wl[k * 64 + 4 * tx];
            float ar[4] = {a4.x, a4.y, a4.z, a4.w};
#pragma unroll
            for (int r = 0; r < 4; ++r) {
                acc[r][0] = fmaf(ar[r], w4.x, acc[r][0]);
                acc[r][1] = fmaf(ar[r], w4.y, acc[r][1]);
                acc[r][2] = fmaf(ar[r], w4.z, acc[r][2]);
                acc[r][3] = fmaf(ar[r], w4.w, acc[r][3]);
            }
        }
    }
    if (tid < 64) rs[tid] = 0.0f;
    __syncthreads();
#pragma unroll
    for (int r = 0; r < 4; ++r) {
        float p = acc[r][0] * acc[r][0] + acc[r][1] * acc[r][1] +
                  acc[r][2] * acc[r][2] + acc[r][3] * acc[r][3];
        atomicAdd(&rs[4 * ty + r], p);
    }
    __syncthreads();
#pragma unroll
    for (int r = 0; r < 4; ++r) {
        int row = n0 + 4 * ty + r;
        if (row < N) {
            float sc = 1.0f / fmaxf(sqrtf(rs[4 * ty + r]), 1e-12f);
            float4 o;
            o.x = acc[r][0] * sc; o.y = acc[r][1] * sc;
            o.z = acc[r][2] * sc; o.w = acc[r][3] * sc;
            *(float4*)&out[(long long)row * 64 + 4 * tx] = o;
        }
    }
}

// ---------------- CSR pull aggregation (fp16 gather, 4-B edge) ----------------
// out[n] = bias + dis[n]^2 * h(xw[n]) + sum_e dis[s]*dis[n] * h(xw[s])
// 12 threads per node, 8 cols (16 B fp16) each, edge loop unrolled x4.

__global__ __launch_bounds__(256) void agg96h(const __half* __restrict__ hxw,
                                              const int* __restrict__ rowptr,
                                              const int* __restrict__ csrc,
                                              const float* __restrict__ dis,
                                              const float* __restrict__ bias,
                                              float* __restrict__ out, int N) {
    int idx = blockIdx.x * 256 + threadIdx.x;
    if (idx >= N * 12) return;
    int n = idx / 12, c8 = idx % 12;
    float dn = dis[n];
    float acc[8];
    {
        float dd = dn * dn;
        float4 g = *(const float4*)&hxw[(long long)n * 96 + c8 * 8];
        const __half2* hs = (const __half2*)&g;
#pragma unroll
        for (int k = 0; k < 4; ++k) {
            float2 f = __half22float2(hs[k]);
            acc[2 * k + 0] = fmaf(f.x, dd, bias[c8 * 8 + 2 * k + 0]);
            acc[2 * k + 1] = fmaf(f.y, dd, bias[c8 * 8 + 2 * k + 1]);
        }
    }
    int e = rowptr[n], e1 = rowptr[n + 1];
    for (; e + 3 < e1; e += 4) {
        int s0 = csrc[e], s1 = csrc[e + 1], s2 = csrc[e + 2], s3 = csrc[e + 3];
        float w0 = dis[s0] * dn, w1 = dis[s1] * dn, w2 = dis[s2] * dn, w3 = dis[s3] * dn;
        float4 g0 = *(const float4*)&hxw[(long long)s0 * 96 + c8 * 8];
        float4 g1 = *(const float4*)&hxw[(long long)s1 * 96 + c8 * 8];
        float4 g2 = *(const float4*)&hxw[(long long)s2 * 96 + c8 * 8];
        float4 g3 = *(const float4*)&hxw[(long long)s3 * 96 + c8 * 8];
        const __half2* h0 = (const __half2*)&g0;
        const __half2* h1 = (const __half2*)&g1;
        const __half2* h2 = (const __half2*)&g2;
        const __half2* h3 = (const __half2*)&g3;
#pragma unroll
        for (int k = 0; k < 4; ++k) {
            float2 f0 = __half22float2(h0[k]);
            float2 f1 = __half22float2(h1[k]);
            float2 f2 = __half22float2(h2[k]);
            float2 f3 = __half22float2(h3[k]);
            acc[2 * k + 0] = fmaf(f0.x, w0, acc[2 * k + 0]);
            acc[2 * k + 1] = fmaf(f0.y, w0, acc[2 * k + 1]);
            acc[2 * k + 0] = fmaf(f1.x, w1, acc[2 * k + 0]);
            acc[2 * k + 1] = fmaf(f1.y, w1, acc[2 * k + 1]);
            acc[2 * k + 0] = fmaf(f2.x, w2, acc[2 * k + 0]);
            acc[2 * k + 1] = fmaf(f2.y, w2, acc[2 * k + 1]);
            acc[2 * k + 0] = fmaf(f3.x, w3, acc[2 * k + 0]);
            acc[2 * k + 1] = fmaf(f3.y, w3, acc[2 * k + 1]);
        }
    }
    for (; e < e1; ++e) {
        int s0 = csrc[e];
        float w0 = dis[s0] * dn;
        float4 g0 = *(const float4*)&hxw[(long long)s0 * 96 + c8 * 8];
        const __half2* h0 = (const __half2*)&g0;
#pragma unroll
        for (int k = 0; k < 4; ++k) {
            float2 f0 = __half22float2(h0[k]);
            acc[2 * k + 0] = fmaf(f0.x, w0, acc[2 * k + 0]);
            acc[2 * k + 1] = fmaf(f0.y, w0, acc[2 * k + 1]);
        }
    }
    float4 o0, o1;
    o0.x = acc[0]; o0.y = acc[1]; o0.z = acc[2]; o0.w = acc[3];
    o1.x = acc[4]; o1.y = acc[5]; o1.z = acc[6]; o1.w = acc[7];
    *(float4*)&out[(long long)n * 96 + c8 * 8] = o0;
    *(float4*)&out[(long long)n * 96 + c8 * 8 + 4] = o1;
}

// ---------------- BN stats (coalesced grid-stride) ----------------

__global__ __launch_bounds__(256) void bn_stats96(const float* __restrict__ h,
                                                  float* __restrict__ sums, int N) {
    __shared__ float sb[192];
    const int tid = threadIdx.x;
    if (tid < 192) sb[tid] = 0.0f;
    __syncthreads();
    int g = blockIdx.x * 256 + tid;
    int total = N * 24, stride = gridDim.x * 256;  // stride multiple of 24
    float4 s4 = {0, 0, 0, 0}, q4 = {0, 0, 0, 0};
    int c4 = g % 24;
    for (int i = g; i < total; i += stride) {
        int n = i / 24;
        float4 v = *(const float4*)&h[n * 96 + 4 * c4];
        s4.x += v.x; s4.y += v.y; s4.z += v.z; s4.w += v.w;
        q4.x += v.x * v.x; q4.y += v.y * v.y; q4.z += v.z * v.z; q4.w += v.w * v.w;
    }
    atomicAdd(&sb[4 * c4 + 0], s4.x);
    atomicAdd(&sb[4 * c4 + 1], s4.y);
    atomicAdd(&sb[4 * c4 + 2], s4.z);
    atomicAdd(&sb[4 * c4 + 3], s4.w);
    atomicAdd(&sb[96 + 4 * c4 + 0], q4.x);
    atomicAdd(&sb[96 + 4 * c4 + 1], q4.y);
    atomicAdd(&sb[96 + 4 * c4 + 2], q4.z);
    atomicAdd(&sb[96 + 4 * c4 + 3], q4.w);
    __syncthreads();
    if (tid < 192) atomicAdd(&sums[tid], sb[tid]);
}

__global__ void bn_finalize96(const float* __restrict__ sums, const float* __restrict__ gamma,
                              const float* __restrict__ beta, float* __restrict__ ss, int N) {
    int i = threadIdx.x;
    if (i < 96) {
        float inv_n = 1.0f / (float)N;
        float mean = sums[i] * inv_n;
        float var = sums[96 + i] * inv_n - mean * mean;
        float sc = gamma[i] * rsqrtf(var + 1e-5f);
        ss[i] = sc;
        ss[96 + i] = beta[i] - mean * sc;
    }
}

// ---------------- launch ----------------

extern "C" void kernel_launch(void* const* d_in, const int* in_sizes, int n_in,
                              void* d_out, int out_size, void* d_ws, size_t ws_size,
                              hipStream_t stream) {
    const float* x   = (const float*)d_in[0];
    const int*   ei  = (const int*)d_in[1];
    const float* W1  = (const float*)d_in[2];
    const float* b1  = (const float*)d_in[3];
    const float* g1  = (const float*)d_in[4];
    const float* be1 = (const float*)d_in[5];
    const float* W2  = (const float*)d_in[6];
    const float* b2  = (const float*)d_in[7];
    const float* g2  = (const float*)d_in[8];
    const float* be2 = (const float*)d_in[9];
    const float* Wp1 = (const float*)d_in[10];
    const float* bp1 = (const float*)d_in[11];
    const float* gp  = (const float*)d_in[12];
    const float* bep = (const float*)d_in[13];
    const float* Wp2 = (const float*)d_in[14];
    const float* bp2 = (const float*)d_in[15];

    const int N = in_sizes[0] / 128;   // 50000
    const int E = in_sizes[1] / 2;     // 800000
    const int* src = ei;
    const int* dst = ei + E;

    // workspace layout (~55 MB)
    char* w = (char*)d_ws;
    auto alloc = [&](size_t bytes) { char* p = w; w += (bytes + 15) & ~size_t(15); return p; };
    int*    cnt    = (int*)alloc((size_t)N * 4);
    int*    rowptr = (int*)alloc((size_t)(N + 1) * 4);
    int*    bsum   = (int*)alloc(64 * 4);
    int*    boff   = (int*)alloc(64 * 4);
    float*  dis    = (float*)alloc((size_t)N * 4);
    int*    eoff   = (int*)alloc((size_t)E * 4);
    int*    csrc   = (int*)alloc((size_t)E * 4);
    float*  buf1   = (float*)alloc((size_t)N * 96 * 4);
    float*  buf2   = (float*)alloc((size_t)N * 96 * 4);
    __half* hbuf   = (__half*)alloc((size_t)N * 96 * 2);
    float*  sums   = (float*)alloc(576 * 4);
    float*  ss     = (float*)alloc(576 * 4);
    float* sums1 = sums, *sums2 = sums + 192, *sums3 = sums + 384;
    float* ss1 = ss, *ss2 = ss + 192, *ss3 = ss + 384;

    float* out = (float*)d_out;

    const int gE  = cdiv(E, BLK);                  // 3125 blocks, 1 edge/thread
    const int gG  = cdiv(N, 64);                   // 782 gemm blocks
    const int gA  = cdiv((long long)N * 12, BLK);  // 2344 agg blocks
    const int nb  = cdiv(N, 1024);                 // scan blocks (49)

    // CSR build (atomic-free 4-B scatter: slot = rowptr[dst] + eoff)
    zero_int<<<cdiv(N, BLK), BLK, 0, stream>>>(cnt, N);
    count_dst_off<<<gE, BLK, 0, stream>>>(dst, cnt, eoff, E);
    scan1_dis<<<nb, 256, 0, stream>>>(cnt, rowptr, bsum, dis, N);
    scan2z<<<1, 640, 0, stream>>>(bsum, boff, nb, sums);
    scan3<<<cdiv(N, BLK), BLK, 0, stream>>>(rowptr, boff, N, E);
    csr_fill<<<gE, BLK, 0, stream>>>(src, dst, eoff, rowptr, csrc, E);

    // layer 1 (GEMM writes fp16 shadow only)
    gemm96<128, false, false, true, false><<<gG, 256, 0, stream>>>(x, W1, nullptr, nullptr,
                                                                   nullptr, hbuf, N);
    agg96h<<<gA, 256, 0, stream>>>(hbuf, rowptr, csrc, dis, b1, buf2, N);
    bn_stats96<<<512, 256, 0, stream>>>(buf2, sums1, N);
    bn_finalize96<<<1, 128, 0, stream>>>(sums1, g1, be1, ss1, N);

    // layer 2 (BN+ReLU of layer 1 fused into A staging; fp16 shadow only)
    gemm96<96, true, false, true, false><<<gG, 256, 0, stream>>>(buf2, W2, nullptr, ss1,
                                                                 nullptr, hbuf, N);
    agg96h<<<gA, 256, 0, stream>>>(hbuf, rowptr, csrc, dis, b2, buf2, N);
    bn_stats96<<<512, 256, 0, stream>>>(buf2, sums2, N);
    bn_finalize96<<<1, 128, 0, stream>>>(sums2, g2, be2, ss2, N);

    // projector linear 1 (BN+ReLU of layer 2 fused; fp32 out)
    gemm96<96, true, true, false, true><<<gG, 256, 0, stream>>>(buf2, Wp1, bp1, ss2,
                                                                buf1, nullptr, N);
    bn_stats96<<<512, 256, 0, stream>>>(buf1, sums3, N);
    bn_finalize96<<<1, 128, 0, stream>>>(sums3, gp, bep, ss3, N);

    // projector linear 2 + fused L2 normalize (BN+ReLU fused)
    gemm_final<<<gG, 256, 0, stream>>>(buf1, Wp2, bp2, ss3, out, N);
}

// Round 9
// 350.656 us; speedup vs baseline: 3.9171x; 1.1163x over previous
//
#include <hip/hip_runtime.h>
#include <hip/hip_fp16.h>

constexpr int BLK = 256;

static inline int cdiv(long long a, int b) { return (int)((a + b - 1) / b); }

using v8h = __attribute__((ext_vector_type(8))) _Float16;
using v4f = __attribute__((ext_vector_type(4))) float;

// ---------------- utility ----------------

__global__ void zero_int(int* __restrict__ p, int n) {
    for (int i = blockIdx.x * blockDim.x + threadIdx.x; i < n; i += gridDim.x * blockDim.x)
        p[i] = 0;
}

// ---------------- degree / CSR build ----------------

__global__ void count_dst_off(const int* __restrict__ dst, int* __restrict__ cnt,
                              int* __restrict__ eoff, int E) {
    for (int i = blockIdx.x * blockDim.x + threadIdx.x; i < E; i += gridDim.x * blockDim.x)
        eoff[i] = atomicAdd(&cnt[dst[i]], 1);
}

// block scans 1024 elements (256 threads x 4); also emits dis = rsqrt(cnt+1)
__global__ void scan1_dis(const int* __restrict__ cnt, int* __restrict__ rowptr,
                          int* __restrict__ bsum, float* __restrict__ dis, int N) {
    __shared__ int ts[256];
    int tid = threadIdx.x;
    int base = blockIdx.x * 1024 + tid * 4;
    int v[4], s = 0;
#pragma unroll
    for (int i = 0; i < 4; ++i) {
        v[i] = (base + i < N) ? cnt[base + i] : 0;
        s += v[i];
        if (base + i < N) dis[base + i] = rsqrtf((float)v[i] + 1.0f);
    }
    ts[tid] = s;
    __syncthreads();
    for (int off = 1; off < 256; off <<= 1) {
        int t = 0;
        if (tid >= off) t = ts[tid - off];
        __syncthreads();
        if (tid >= off) ts[tid] += t;
        __syncthreads();
    }
    int run = ts[tid] - s;
#pragma unroll
    for (int i = 0; i < 4; ++i) {
        if (base + i < N) rowptr[base + i] = run;
        run += v[i];
    }
    if (tid == 255) bsum[blockIdx.x] = ts[255];
}

// wave shuffle-scan over block sums (nb <= 64) + zero the BN sums buffer
__global__ void scan2z(const int* __restrict__ bsum, int* __restrict__ boff, int nb,
                       float* __restrict__ sums) {
    int tid = threadIdx.x;  // 640 threads
    if (tid < 64) {
        int orig = (tid < nb) ? bsum[tid] : 0;
        int v = orig;
#pragma unroll
        for (int off = 1; off < 64; off <<= 1) {
            int t = __shfl_up(v, off, 64);
            if (tid >= off) v += t;
        }
        if (tid < nb) boff[tid] = v - orig;  // exclusive
    } else if (tid < 64 + 576) {
        sums[tid - 64] = 0.0f;
    }
}

__global__ void scan3(int* __restrict__ rowptr, const int* __restrict__ boff, int N, int E) {
    int i = blockIdx.x * blockDim.x + threadIdx.x;
    if (i < N) rowptr[i] += boff[i >> 10];
    if (i == 0) rowptr[N] = E;
}

// atomic-free scatter of 4-B src index: slot = rowptr[dst] + eoff (bijection)
__global__ void csr_fill(const int* __restrict__ src, const int* __restrict__ dst,
                         const int* __restrict__ eoff, const int* __restrict__ rowptr,
                         int* __restrict__ csrc, int E) {
    for (int i = blockIdx.x * blockDim.x + threadIdx.x; i < E; i += gridDim.x * blockDim.x) {
        csrc[rowptr[dst[i]] + eoff[i]] = src[i];
    }
}

// ---------------- MFMA GEMM: act(in)[N,K] @ W[K,96] (+bias) -----------------
// A: fp32 -> BN+ReLU -> fp16 frags in regs (A[m=lane&15][k=quad*8+j]).
// B: W transposed fp16 in LDS (Wt[n][k], LDK=K+8), staged once -> 1 barrier.
// C/D: col=lane&15, row=quad*4+reg. Block = 4 waves x 16 rows = 64 rows.

template <int K, bool ACT, bool BIAS, bool HOUT, bool WOUT>
__global__ __launch_bounds__(256) void gemm96m(const float* __restrict__ in,
                                               const float* __restrict__ W,
                                               const float* __restrict__ bias,
                                               const float* __restrict__ ss,
                                               float* __restrict__ out,
                                               _Float16* __restrict__ hout, int N) {
    constexpr int NK = K / 32;      // K-chunks of 32
    constexpr int LDK = K + 8;      // pad: 2-way bank alias only (free)
    __shared__ __align__(16) _Float16 Wt[96 * LDK];
    const int tid = threadIdx.x;
    // stage W transposed (coalesced global read, scattered 2-B LDS write, once)
    for (int idx = tid; idx < K * 96; idx += 256) {
        int k = idx / 96, n = idx - k * 96;
        Wt[n * LDK + k] = (_Float16)W[idx];
    }
    __syncthreads();

    const int wave = tid >> 6, lane = tid & 63;
    const int quad = lane >> 4, lm = lane & 15;
    const int rbase = blockIdx.x * 64 + wave * 16;
    int arow = rbase + lm;
    arow = arow < N ? arow : N - 1;

    v8h afr[NK];
#pragma unroll
    for (int kc = 0; kc < NK; ++kc) {
        const float* p = &in[(long long)arow * K + kc * 32 + quad * 8];
        float4 p0 = *(const float4*)p;
        float4 p1 = *(const float4*)(p + 4);
        if (ACT) {
            int kk = kc * 32 + quad * 8;
            float4 sc0 = *(const float4*)&ss[kk];
            float4 sc1 = *(const float4*)&ss[kk + 4];
            float4 sh0 = *(const float4*)&ss[96 + kk];
            float4 sh1 = *(const float4*)&ss[96 + kk + 4];
            p0.x = fmaxf(fmaf(p0.x, sc0.x, sh0.x), 0.0f);
            p0.y = fmaxf(fmaf(p0.y, sc0.y, sh0.y), 0.0f);
            p0.z = fmaxf(fmaf(p0.z, sc0.z, sh0.z), 0.0f);
            p0.w = fmaxf(fmaf(p0.w, sc0.w, sh0.w), 0.0f);
            p1.x = fmaxf(fmaf(p1.x, sc1.x, sh1.x), 0.0f);
            p1.y = fmaxf(fmaf(p1.y, sc1.y, sh1.y), 0.0f);
            p1.z = fmaxf(fmaf(p1.z, sc1.z, sh1.z), 0.0f);
            p1.w = fmaxf(fmaf(p1.w, sc1.w, sh1.w), 0.0f);
        }
        v8h a;
        a[0] = (_Float16)p0.x; a[1] = (_Float16)p0.y;
        a[2] = (_Float16)p0.z; a[3] = (_Float16)p0.w;
        a[4] = (_Float16)p1.x; a[5] = (_Float16)p1.y;
        a[6] = (_Float16)p1.z; a[7] = (_Float16)p1.w;
        afr[kc] = a;
    }

    v4f acc[6];
#pragma unroll
    for (int t = 0; t < 6; ++t) {
        v4f c = {0.0f, 0.0f, 0.0f, 0.0f};
#pragma unroll
        for (int kc = 0; kc < NK; ++kc) {
            v8h b = *(const v8h*)&Wt[(t * 16 + lm) * LDK + kc * 32 + quad * 8];
            c = __builtin_amdgcn_mfma_f32_16x16x32_f16(afr[kc], b, c, 0, 0, 0);
        }
        acc[t] = c;
    }

#pragma unroll
    for (int t = 0; t < 6; ++t) {
        float bv = BIAS ? bias[t * 16 + lm] : 0.0f;
#pragma unroll
        for (int r = 0; r < 4; ++r) {
            int gr = rbase + quad * 4 + r;
            if (gr < N) {
                float o = acc[t][r] + bv;
                if (WOUT) out[(long long)gr * 96 + t * 16 + lm] = o;
                if (HOUT) hout[(long long)gr * 96 + t * 16 + lm] = (_Float16)o;
            }
        }
    }
}

// ---------------- MFMA final GEMM: l2norm(act(in) @ Wp2[96,64] + bp2) -------

__global__ __launch_bounds__(256) void gemm_finalm(const float* __restrict__ in,
                                                   const float* __restrict__ W,
                                                   const float* __restrict__ bias,
                                                   const float* __restrict__ ss,
                                                   float* __restrict__ out, int N) {
    constexpr int K = 96, NK = 3, LDK = K + 8;
    __shared__ __align__(16) _Float16 Wt[64 * LDK];
    const int tid = threadIdx.x;
    for (int idx = tid; idx < K * 64; idx += 256) {
        int k = idx / 64, n = idx - k * 64;
        Wt[n * LDK + k] = (_Float16)W[idx];
    }
    __syncthreads();

    const int wave = tid >> 6, lane = tid & 63;
    const int quad = lane >> 4, lm = lane & 15;
    const int rbase = blockIdx.x * 64 + wave * 16;
    int arow = rbase + lm;
    arow = arow < N ? arow : N - 1;

    v8h afr[NK];
#pragma unroll
    for (int kc = 0; kc < NK; ++kc) {
        const float* p = &in[(long long)arow * K + kc * 32 + quad * 8];
        float4 p0 = *(const float4*)p;
        float4 p1 = *(const float4*)(p + 4);
        int kk = kc * 32 + quad * 8;
        float4 sc0 = *(const float4*)&ss[kk];
        float4 sc1 = *(const float4*)&ss[kk + 4];
        float4 sh0 = *(const float4*)&ss[96 + kk];
        float4 sh1 = *(const float4*)&ss[96 + kk + 4];
        p0.x = fmaxf(fmaf(p0.x, sc0.x, sh0.x), 0.0f);
        p0.y = fmaxf(fmaf(p0.y, sc0.y, sh0.y), 0.0f);
        p0.z = fmaxf(fmaf(p0.z, sc0.z, sh0.z), 0.0f);
        p0.w = fmaxf(fmaf(p0.w, sc0.w, sh0.w), 0.0f);
        p1.x = fmaxf(fmaf(p1.x, sc1.x, sh1.x), 0.0f);
        p1.y = fmaxf(fmaf(p1.y, sc1.y, sh1.y), 0.0f);
        p1.z = fmaxf(fmaf(p1.z, sc1.z, sh1.z), 0.0f);
        p1.w = fmaxf(fmaf(p1.w, sc1.w, sh1.w), 0.0f);
        v8h a;
        a[0] = (_Float16)p0.x; a[1] = (_Float16)p0.y;
        a[2] = (_Float16)p0.z; a[3] = (_Float16)p0.w;
        a[4] = (_Float16)p1.x; a[5] = (_Float16)p1.y;
        a[6] = (_Float16)p1.z; a[7] = (_Float16)p1.w;
        afr[kc] = a;
    }

    v4f acc[4];
#pragma unroll
    for (int t = 0; t < 4; ++t) {
        v4f c = {0.0f, 0.0f, 0.0f, 0.0f};
#pragma unroll
        for (int kc = 0; kc < NK; ++kc) {
            v8h b = *(const v8h*)&Wt[(t * 16 + lm) * LDK + kc * 32 + quad * 8];
            c = __builtin_amdgcn_mfma_f32_16x16x32_f16(afr[kc], b, c, 0, 0, 0);
        }
        float bv = bias[t * 16 + lm];
        c[0] += bv; c[1] += bv; c[2] += bv; c[3] += bv;
        acc[t] = c;
    }

    // row-wise L2 norm: reduce sum of squares across the 16 lanes of each quad
    float sq[4];
#pragma unroll
    for (int r = 0; r < 4; ++r) {
        float s = acc[0][r] * acc[0][r] + acc[1][r] * acc[1][r] +
                  acc[2][r] * acc[2][r] + acc[3][r] * acc[3][r];
#pragma unroll
        for (int m = 1; m < 16; m <<= 1) s += __shfl_xor(s, m, 64);
        sq[r] = 1.0f / fmaxf(sqrtf(s), 1e-12f);
    }
#pragma unroll
    for (int r = 0; r < 4; ++r) {
        int gr = rbase + quad * 4 + r;
        if (gr < N) {
#pragma unroll
            for (int t = 0; t < 4; ++t)
                out[(long long)gr * 64 + t * 16 + lm] = acc[t][r] * sq[r];
        }
    }
}

// ---------------- CSR pull aggregation (fp16 gather, 4-B edge) ----------------
// out[n] = bias + dis[n]^2 * h(xw[n]) + sum_e dis[s]*dis[n] * h(xw[s])
// 12 threads per node, 8 cols (16 B fp16) each, edge loop unrolled x4.

__global__ __launch_bounds__(256) void agg96h(const __half* __restrict__ hxw,
                                              const int* __restrict__ rowptr,
                                              const int* __restrict__ csrc,
                                              const float* __restrict__ dis,
                                              const float* __restrict__ bias,
                                              float* __restrict__ out, int N) {
    int idx = blockIdx.x * 256 + threadIdx.x;
    if (idx >= N * 12) return;
    int n = idx / 12, c8 = idx % 12;
    float dn = dis[n];
    float acc[8];
    {
        float dd = dn * dn;
        float4 g = *(const float4*)&hxw[(long long)n * 96 + c8 * 8];
        const __half2* hs = (const __half2*)&g;
#pragma unroll
        for (int k = 0; k < 4; ++k) {
            float2 f = __half22float2(hs[k]);
            acc[2 * k + 0] = fmaf(f.x, dd, bias[c8 * 8 + 2 * k + 0]);
            acc[2 * k + 1] = fmaf(f.y, dd, bias[c8 * 8 + 2 * k + 1]);
        }
    }
    int e = rowptr[n], e1 = rowptr[n + 1];
    for (; e + 3 < e1; e += 4) {
        int s0 = csrc[e], s1 = csrc[e + 1], s2 = csrc[e + 2], s3 = csrc[e + 3];
        float w0 = dis[s0] * dn, w1 = dis[s1] * dn, w2 = dis[s2] * dn, w3 = dis[s3] * dn;
        float4 g0 = *(const float4*)&hxw[(long long)s0 * 96 + c8 * 8];
        float4 g1 = *(const float4*)&hxw[(long long)s1 * 96 + c8 * 8];
        float4 g2 = *(const float4*)&hxw[(long long)s2 * 96 + c8 * 8];
        float4 g3 = *(const float4*)&hxw[(long long)s3 * 96 + c8 * 8];
        const __half2* h0 = (const __half2*)&g0;
        const __half2* h1 = (const __half2*)&g1;
        const __half2* h2 = (const __half2*)&g2;
        const __half2* h3 = (const __half2*)&g3;
#pragma unroll
        for (int k = 0; k < 4; ++k) {
            float2 f0 = __half22float2(h0[k]);
            float2 f1 = __half22float2(h1[k]);
            float2 f2 = __half22float2(h2[k]);
            float2 f3 = __half22float2(h3[k]);
            acc[2 * k + 0] = fmaf(f0.x, w0, acc[2 * k + 0]);
            acc[2 * k + 1] = fmaf(f0.y, w0, acc[2 * k + 1]);
            acc[2 * k + 0] = fmaf(f1.x, w1, acc[2 * k + 0]);
            acc[2 * k + 1] = fmaf(f1.y, w1, acc[2 * k + 1]);
            acc[2 * k + 0] = fmaf(f2.x, w2, acc[2 * k + 0]);
            acc[2 * k + 1] = fmaf(f2.y, w2, acc[2 * k + 1]);
            acc[2 * k + 0] = fmaf(f3.x, w3, acc[2 * k + 0]);
            acc[2 * k + 1] = fmaf(f3.y, w3, acc[2 * k + 1]);
        }
    }
    for (; e < e1; ++e) {
        int s0 = csrc[e];
        float w0 = dis[s0] * dn;
        float4 g0 = *(const float4*)&hxw[(long long)s0 * 96 + c8 * 8];
        const __half2* h0 = (const __half2*)&g0;
#pragma unroll
        for (int k = 0; k < 4; ++k) {
            float2 f0 = __half22float2(h0[k]);
            acc[2 * k + 0] = fmaf(f0.x, w0, acc[2 * k + 0]);
            acc[2 * k + 1] = fmaf(f0.y, w0, acc[2 * k + 1]);
        }
    }
    float4 o0, o1;
    o0.x = acc[0]; o0.y = acc[1]; o0.z = acc[2]; o0.w = acc[3];
    o1.x = acc[4]; o1.y = acc[5]; o1.z = acc[6]; o1.w = acc[7];
    *(float4*)&out[(long long)n * 96 + c8 * 8] = o0;
    *(float4*)&out[(long long)n * 96 + c8 * 8 + 4] = o1;
}

// ---------------- BN stats (coalesced grid-stride) ----------------

__global__ __launch_bounds__(256) void bn_stats96(const float* __restrict__ h,
                                                  float* __restrict__ sums, int N) {
    __shared__ float sb[192];
    const int tid = threadIdx.x;
    if (tid < 192) sb[tid] = 0.0f;
    __syncthreads();
    int g = blockIdx.x * 256 + tid;
    int total = N * 24, stride = gridDim.x * 256;  // stride multiple of 24
    float4 s4 = {0, 0, 0, 0}, q4 = {0, 0, 0, 0};
    int c4 = g % 24;
    for (int i = g; i < total; i += stride) {
        int n = i / 24;
        float4 v = *(const float4*)&h[n * 96 + 4 * c4];
        s4.x += v.x; s4.y += v.y; s4.z += v.z; s4.w += v.w;
        q4.x += v.x * v.x; q4.y += v.y * v.y; q4.z += v.z * v.z; q4.w += v.w * v.w;
    }
    atomicAdd(&sb[4 * c4 + 0], s4.x);
    atomicAdd(&sb[4 * c4 + 1], s4.y);
    atomicAdd(&sb[4 * c4 + 2], s4.z);
    atomicAdd(&sb[4 * c4 + 3], s4.w);
    atomicAdd(&sb[96 + 4 * c4 + 0], q4.x);
    atomicAdd(&sb[96 + 4 * c4 + 1], q4.y);
    atomicAdd(&sb[96 + 4 * c4 + 2], q4.z);
    atomicAdd(&sb[96 + 4 * c4 + 3], q4.w);
    __syncthreads();
    if (tid < 192) atomicAdd(&sums[tid], sb[tid]);
}

__global__ void bn_finalize96(const float* __restrict__ sums, const float* __restrict__ gamma,
                              const float* __restrict__ beta, float* __restrict__ ss, int N) {
    int i = threadIdx.x;
    if (i < 96) {
        float inv_n = 1.0f / (float)N;
        float mean = sums[i] * inv_n;
        float var = sums[96 + i] * inv_n - mean * mean;
        float sc = gamma[i] * rsqrtf(var + 1e-5f);
        ss[i] = sc;
        ss[96 + i] = beta[i] - mean * sc;
    }
}

// ---------------- launch ----------------

extern "C" void kernel_launch(void* const* d_in, const int* in_sizes, int n_in,
                              void* d_out, int out_size, void* d_ws, size_t ws_size,
                              hipStream_t stream) {
    const float* x   = (const float*)d_in[0];
    const int*   ei  = (const int*)d_in[1];
    const float* W1  = (const float*)d_in[2];
    const float* b1  = (const float*)d_in[3];
    const float* g1  = (const float*)d_in[4];
    const float* be1 = (const float*)d_in[5];
    const float* W2  = (const float*)d_in[6];
    const float* b2  = (const float*)d_in[7];
    const float* g2  = (const float*)d_in[8];
    const float* be2 = (const float*)d_in[9];
    const float* Wp1 = (const float*)d_in[10];
    const float* bp1 = (const float*)d_in[11];
    const float* gp  = (const float*)d_in[12];
    const float* bep = (const float*)d_in[13];
    const float* Wp2 = (const float*)d_in[14];
    const float* bp2 = (const float*)d_in[15];

    const int N = in_sizes[0] / 128;   // 50000
    const int E = in_sizes[1] / 2;     // 800000
    const int* src = ei;
    const int* dst = ei + E;

    // workspace layout (~55 MB)
    char* w = (char*)d_ws;
    auto alloc = [&](size_t bytes) { char* p = w; w += (bytes + 15) & ~size_t(15); return p; };
    int*      cnt    = (int*)alloc((size_t)N * 4);
    int*      rowptr = (int*)alloc((size_t)(N + 1) * 4);
    int*      bsum   = (int*)alloc(64 * 4);
    int*      boff   = (int*)alloc(64 * 4);
    float*    dis    = (float*)alloc((size_t)N * 4);
    int*      eoff   = (int*)alloc((size_t)E * 4);
    int*      csrc   = (int*)alloc((size_t)E * 4);
    float*    buf1   = (float*)alloc((size_t)N * 96 * 4);
    float*    buf2   = (float*)alloc((size_t)N * 96 * 4);
    _Float16* hbuf   = (_Float16*)alloc((size_t)N * 96 * 2);
    float*    sums   = (float*)alloc(576 * 4);
    float*    ss     = (float*)alloc(576 * 4);
    float* sums1 = sums, *sums2 = sums + 192, *sums3 = sums + 384;
    float* ss1 = ss, *ss2 = ss + 192, *ss3 = ss + 384;

    float* out = (float*)d_out;

    const int gE  = cdiv(E, BLK);                  // 3125 blocks, 1 edge/thread
    const int gG  = cdiv(N, 64);                   // 782 gemm blocks
    const int gA  = cdiv((long long)N * 12, BLK);  // 2344 agg blocks
    const int nb  = cdiv(N, 1024);                 // scan blocks (49)

    // CSR build (atomic-free 4-B scatter: slot = rowptr[dst] + eoff)
    zero_int<<<cdiv(N, BLK), BLK, 0, stream>>>(cnt, N);
    count_dst_off<<<gE, BLK, 0, stream>>>(dst, cnt, eoff, E);
    scan1_dis<<<nb, 256, 0, stream>>>(cnt, rowptr, bsum, dis, N);
    scan2z<<<1, 640, 0, stream>>>(bsum, boff, nb, sums);
    scan3<<<cdiv(N, BLK), BLK, 0, stream>>>(rowptr, boff, N, E);
    csr_fill<<<gE, BLK, 0, stream>>>(src, dst, eoff, rowptr, csrc, E);

    // layer 1 (MFMA GEMM writes fp16 shadow only)
    gemm96m<128, false, false, true, false><<<gG, 256, 0, stream>>>(x, W1, nullptr, nullptr,
                                                                    nullptr, hbuf, N);
    agg96h<<<gA, 256, 0, stream>>>((const __half*)hbuf, rowptr, csrc, dis, b1, buf2, N);
    bn_stats96<<<512, 256, 0, stream>>>(buf2, sums1, N);
    bn_finalize96<<<1, 128, 0, stream>>>(sums1, g1, be1, ss1, N);

    // layer 2 (BN+ReLU fused into A fragments; fp16 shadow only)
    gemm96m<96, true, false, true, false><<<gG, 256, 0, stream>>>(buf2, W2, nullptr, ss1,
                                                                  nullptr, hbuf, N);
    agg96h<<<gA, 256, 0, stream>>>((const __half*)hbuf, rowptr, csrc, dis, b2, buf2, N);
    bn_stats96<<<512, 256, 0, stream>>>(buf2, sums2, N);
    bn_finalize96<<<1, 128, 0, stream>>>(sums2, g2, be2, ss2, N);

    // projector linear 1 (BN+ReLU fused; fp32 out)
    gemm96m<96, true, true, false, true><<<gG, 256, 0, stream>>>(buf2, Wp1, bp1, ss2,
                                                                 buf1, nullptr, N);
    bn_stats96<<<512, 256, 0, stream>>>(buf1, sums3, N);
    bn_finalize96<<<1, 128, 0, stream>>>(sums3, gp, bep, ss3, N);

    // projector linear 2 + fused L2 normalize (BN+ReLU fused, MFMA)
    gemm_finalm<<<gG, 256, 0, stream>>>(buf1, Wp2, bp2, ss3, out, N);
}